// Round 6
// baseline (528.651 us; speedup 1.0000x reference)
//
#include <hip/hip_runtime.h>

#define NPTS 512
#define DIM  256
#define HID  128
#define NSEG 64
#define LN_EPS 1e-5f

typedef short s16x4 __attribute__((ext_vector_type(4)));
typedef short s16x8 __attribute__((ext_vector_type(8)));
typedef float f32x4 __attribute__((ext_vector_type(4)));
typedef const float* fpc;

__device__ __forceinline__ unsigned short f2bf(float f) {
  unsigned int u = __builtin_bit_cast(unsigned int, f);
  u += 0x7FFFu + ((u >> 16) & 1u);
  return (unsigned short)(u >> 16);
}

// ---------------- K02: k0 prep + k2 aggregator (mg-free) + mgsum zero --------------------
__global__ void k02_prep_agg(
    fpc ge_w1, fpc ge_b1, fpc ge_w2, fpc ge_b2,
    fpc features, const int* __restrict__ labels,
    fpc ag_w1, fpc ag_b1, fpc ag_g1, fpc ag_be1,
    fpc ag_w2, fpc ag_b2, fpc ag_g2, fpc ag_be2,
    unsigned short* __restrict__ gmw, float* __restrict__ uw,
    float* __restrict__ tvw, float* __restrict__ scw, float* __restrict__ qfw,
    float* __restrict__ comb, float* __restrict__ cntf, float* __restrict__ mgsum)
{
  const int blk = blockIdx.x;
  const int t = threadIdx.x;
  if (blk < 130) {                       // ---- prep (t<128 active)
    if (t < 128) {
      if (blk < 128) {
        const int c = blk;
        float acc = 0.f;
        for (int d = 0; d < DIM; ++d) acc += ge_w2[d * HID + c] * ge_w2[d * HID + t];
        gmw[c * HID + t] = f2bf(acc);
      } else if (blk == 128) {
        float uu = 0.f, tv = 0.f;
        for (int d = 0; d < DIM; ++d) { const float w = ge_w2[d * HID + t]; uu += w; tv += ge_b2[d] * w; }
        uw[t] = uu; tvw[t] = tv;
        if (t == 0) {
          float s = 0.f, s2 = 0.f;
          for (int d = 0; d < DIM; ++d) { const float bb = ge_b2[d]; s += bb; s2 += bb * bb; }
          scw[0] = s; scw[1] = s2;
        }
      } else {
        if (t < 101) {
          float acc = 0.f;
          if (t < 81) {
            const int a = t / 9, c = t % 9;
            for (int h = 0; h < HID; ++h) acc += ge_w1[h * 9 + a] * ge_w1[h * 9 + c];
            qfw[a * 12 + c] = acc;
          } else if (t < 90) {
            const int a = t - 81;
            for (int h = 0; h < HID; ++h) acc += ge_w1[h * 9 + a];
            qfw[108 + a] = acc;
          } else if (t < 99) {
            const int a = t - 90;
            for (int h = 0; h < HID; ++h) acc += ge_b1[h] * ge_w1[h * 9 + a];
            qfw[117 + a] = acc;
          } else if (t == 99) {
            float acc2 = 0.f;
            for (int h = 0; h < HID; ++h) acc2 += ge_b1[h];
            qfw[126] = acc2;
          } else {
            float acc2 = 0.f;
            for (int h = 0; h < HID; ++h) acc2 += ge_b1[h] * ge_b1[h];
            qfw[127] = acc2;
          }
        }
      }
    }
    return;
  }
  const int item = blk - 130;
  const int lane = t & 63;
  const int wid = t >> 6;
  const int b = item >> 6;
  const int s = item & 63;
  __shared__ __align__(16) int labS[NPTS];
  __shared__ __align__(16) float mfS[DIM];
  __shared__ __align__(16) float h1S[HID];
  __shared__ __align__(16) float red[8];
  mgsum[(b * NSEG + s) * DIM + t] = 0.f;
  for (int n = t; n < NPTS; n += 256) labS[n] = labels[b * NPTS + n];
  __syncthreads();
  float accf = 0.f;
  int cnt = 0;
  for (int n = 0; n < NPTS; n += 4) {
    const int4 l4 = *(const int4*)&labS[n];
    if (l4.x == s) { cnt++; accf += features[(b * NPTS + n + 0) * DIM + t]; }
    if (l4.y == s) { cnt++; accf += features[(b * NPTS + n + 1) * DIM + t]; }
    if (l4.z == s) { cnt++; accf += features[(b * NPTS + n + 2) * DIM + t]; }
    if (l4.w == s) { cnt++; accf += features[(b * NPTS + n + 3) * DIM + t]; }
  }
  const float denom = fmaxf((float)cnt, 1.f);
  mfS[t] = accf / denom;
  __syncthreads();
  float hval = 0.f;
  if (t < HID) {
    float o = ag_b1[t];
    for (int k = 0; k < DIM; k += 4) {
      const f32x4 x = *(const f32x4*)&mfS[k];
      const f32x4 w = *(const f32x4*)&ag_w1[t * DIM + k];
      o += x[0] * w[0] + x[1] * w[1] + x[2] * w[2] + x[3] * w[3];
    }
    hval = o;
  }
  float sv = (t < HID) ? hval : 0.f;
  float qv = (t < HID) ? hval * hval : 0.f;
  #pragma unroll
  for (int off = 1; off < 64; off <<= 1) { sv += __shfl_xor(sv, off); qv += __shfl_xor(qv, off); }
  if (lane == 0 && wid < 2) { red[wid * 2] = sv; red[wid * 2 + 1] = qv; }
  __syncthreads();
  if (t < HID) {
    const float s1 = red[0] + red[2], q1 = red[1] + red[3];
    const float mean = s1 * (1.f / 128.f);
    const float var = fmaxf(q1 * (1.f / 128.f) - mean * mean, 0.f);
    const float rs = rsqrtf(var + LN_EPS);
    h1S[t] = fmaxf((hval - mean) * rs * ag_g1[t] + ag_be1[t], 0.f);
  }
  __syncthreads();
  float o = ag_b2[t];
  for (int k = 0; k < HID; k += 4) {
    const f32x4 x = *(const f32x4*)&h1S[k];
    const f32x4 w = *(const f32x4*)&ag_w2[t * HID + k];
    o += x[0] * w[0] + x[1] * w[1] + x[2] * w[2] + x[3] * w[3];
  }
  float sv2 = o, qv2 = o * o;
  #pragma unroll
  for (int off = 1; off < 64; off <<= 1) { sv2 += __shfl_xor(sv2, off); qv2 += __shfl_xor(qv2, off); }
  if (lane == 0) { red[wid * 2] = sv2; red[wid * 2 + 1] = qv2; }
  __syncthreads();
  const float sa = red[0] + red[2] + red[4] + red[6];
  const float qa = red[1] + red[3] + red[5] + red[7];
  const float mean = sa * (1.f / 256.f);
  const float var = fmaxf(qa * (1.f / 256.f) - mean * mean, 0.f);
  const float rs = rsqrtf(var + LN_EPS);
  comb[(b * NSEG + s) * DIM + t] = (o - mean) * rs * ag_g2[t] + ag_be2[t];
  if (t == 0) cntf[b * NSEG + s] = (float)cnt;
}

// ---------------- K1: v6 core + mgsum atomics + fused K/V row projection ------------------
// geo_ctx global write dropped (no consumer); K/V rows computed from LDS gS at epilogue.
__global__ __launch_bounds__(256, 4) void k1_geo(
    fpc coords, const int* __restrict__ labels,
    fpc g1, fpc be1, fpc w1, fpc b1,
    fpc w2, fpc b2, fpc g2, fpc be2,
    fpc wk, fpc bk, fpc wv, fpc bv,
    const unsigned short* __restrict__ gmw, fpc uw, fpc tvw, fpc scw, fpc qfw,
    float* __restrict__ Kout, float* __restrict__ Vout, float* __restrict__ mgsum)
{
  const int t = threadIdx.x;
  const int lane = t & 63;
  const int wid = t >> 6;
  const int bi = blockIdx.x;           // b*512 + i
  const int b = bi >> 9;

  __shared__ __align__(16) float xs[NPTS][8];
  __shared__ __align__(16) float st[NPTS][2];
  __shared__ __align__(16) float qf[128];
  __shared__ __align__(16) unsigned short h1s[32][136];
  __shared__ __align__(16) float red2[32][12];
  __shared__ __align__(16) float haS[128];
  __shared__ __align__(16) float gS[256];
  __shared__ float srsS, srmS;

  if (t < 128) qf[t] = qfw[t];

  float w1r[2][7], b1r[2], g1r[2], be1r[2];
  #pragma unroll
  for (int r = 0; r < 2; ++r) {
    const int hh = lane * 2 + r;
    w1r[r][0] = w1[hh * 9 + 0]; w1r[r][1] = w1[hh * 9 + 1];
    w1r[r][2] = w1[hh * 9 + 2]; w1r[r][3] = w1[hh * 9 + 3];
    w1r[r][4] = w1[hh * 9 + 6]; w1r[r][5] = w1[hh * 9 + 7];
    w1r[r][6] = w1[hh * 9 + 8];
    b1r[r] = b1[hh]; g1r[r] = g1[hh]; be1r[r] = be1[hh];
  }
  const int n16 = lane & 15;
  const int q16 = lane >> 4;
  const int colc0 = wid * 32 + n16;
  s16x8 gfrag[2][4];
  float u_c[2], tv_c[2];
  #pragma unroll
  for (int dt = 0; dt < 2; ++dt) {
    const int c = colc0 + dt * 16;
    u_c[dt] = uw[c];
    tv_c[dt] = 2.f * tvw[c];
    #pragma unroll
    for (int kt = 0; kt < 4; ++kt)
      gfrag[dt][kt] = *(const s16x8*)&gmw[c * HID + kt * 32 + q16 * 8];
  }
  const float sb = scw[0], sb2 = scw[1];
  const float cix = coords[bi * 3 + 0];
  const float ciy = coords[bi * 3 + 1];
  const float ciz = coords[bi * 3 + 2];
  __syncthreads();

  #pragma unroll
  for (int jj = 0; jj < 2; ++jj) {
    const int j = t + jj * 256;
    const float cjx = coords[(b * NPTS + j) * 3 + 0];
    const float cjy = coords[(b * NPTS + j) * 3 + 1];
    const float cjz = coords[(b * NPTS + j) * 3 + 2];
    const float rx = cix - cjx, ry = ciy - cjy, rz = ciz - cjz;
    const float dist = sqrtf(rx * rx + ry * ry + rz * rz);
    const float inv = 1.f / fmaxf(dist, 1e-12f);
    const float r0 = rx * inv, r1 = ry * inv, r2 = rz * inv;
    const float x0 = dist, x1 = r0, x2 = r1, x3 = r2;
    const float x6 = r1 * r2, x7 = r0 * r1, x8 = r0 * r2;
    float S1 = qf[126] + qf[108] * x0 + qf[109] * x1 + qf[110] * x2 + qf[111] * x3
             + qf[114] * x6 + qf[115] * x7 + qf[116] * x8;
    float tx = qf[117] * x0 + qf[118] * x1 + qf[119] * x2 + qf[120] * x3
             + qf[123] * x6 + qf[124] * x7 + qf[125] * x8;
    const float xv[9] = {x0, x1, x2, x3, 0.f, 0.f, x6, x7, x8};
    float quad = 0.f;
    #pragma unroll
    for (int a = 0; a < 9; ++a) {
      if (a == 4 || a == 5) continue;
      const f32x4 q0 = *(const f32x4*)&qf[a * 12];
      const f32x4 q1 = *(const f32x4*)&qf[a * 12 + 4];
      const f32x4 q2 = *(const f32x4*)&qf[a * 12 + 8];
      const float ya = q0[0] * x0 + q0[1] * x1 + q0[2] * x2 + q0[3] * x3
                     + q1[2] * x6 + q1[3] * x7 + q2[0] * x8;
      quad += ya * xv[a];
    }
    const float S2 = quad + 2.f * tx + qf[127];
    const float mean = S1 * (1.f / 128.f);
    const float var = fmaxf(S2 * (1.f / 128.f) - mean * mean, 0.f);
    st[j][0] = mean;
    st[j][1] = rsqrtf(var + LN_EPS);
    f32x4 X0; X0[0] = x0; X0[1] = x1; X0[2] = x2; X0[3] = x3;
    f32x4 X1; X1[0] = x6; X1[1] = x7; X1[2] = x8; X1[3] = 0.f;
    *(f32x4*)&xs[j][0] = X0;
    *(f32x4*)&xs[j][4] = X1;
  }
  __syncthreads();

  float haL[2] = {0.f, 0.f};
  float srs = 0.f, srm = 0.f;
  const bool own = (wid == 0) && (n16 == 0);

  for (int jb = 0; jb < NPTS; jb += 32) {
    #pragma unroll
    for (int sr = 0; sr < 8; ++sr) {
      const int m = sr * 4 + wid;
      const int j = jb + m;
      const f32x4 X0 = *(const f32x4*)&xs[j][0];
      const f32x4 X1 = *(const f32x4*)&xs[j][4];
      const float2 ms = *(const float2*)&st[j][0];
      unsigned int pk = 0;
      #pragma unroll
      for (int r = 0; r < 2; ++r) {
        const float a = b1r[r]
          + X0[0] * w1r[r][0] + X0[1] * w1r[r][1] + X0[2] * w1r[r][2] + X0[3] * w1r[r][3]
          + X1[0] * w1r[r][4] + X1[1] * w1r[r][5] + X1[2] * w1r[r][6];
        const float e = (a - ms.x) * ms.y * g1r[r] + be1r[r];
        pk |= ((unsigned int)f2bf(fmaxf(e, 0.f))) << (16 * r);
      }
      *(unsigned int*)&h1s[m][lane * 2] = pk;
    }
    __syncthreads();
    f32x4 acc2[2][2];
    #pragma unroll
    for (int mt = 0; mt < 2; ++mt)
      #pragma unroll
      for (int dt = 0; dt < 2; ++dt) {
        f32x4 z; z[0] = tv_c[dt]; z[1] = tv_c[dt]; z[2] = tv_c[dt]; z[3] = tv_c[dt];
        acc2[mt][dt] = z;
      }
    #pragma unroll
    for (int mt = 0; mt < 2; ++mt)
      #pragma unroll
      for (int kt = 0; kt < 4; ++kt) {
        const s16x8 af = *(const s16x8*)&h1s[mt * 16 + n16][kt * 32 + q16 * 8];
        #pragma unroll
        for (int dt = 0; dt < 2; ++dt)
          acc2[mt][dt] = __builtin_amdgcn_mfma_f32_16x16x32_bf16(af, gfrag[dt][kt], acc2[mt][dt], 0, 0, 0);
      }
    float h1v[2][2][4];
    #pragma unroll
    for (int mt = 0; mt < 2; ++mt)
      #pragma unroll
      for (int dt = 0; dt < 2; ++dt)
        #pragma unroll
        for (int r = 0; r < 4; ++r) {
          const unsigned short hv = h1s[mt * 16 + q16 * 4 + r][colc0 + dt * 16];
          h1v[mt][dt][r] = __builtin_bit_cast(float, ((unsigned int)hv) << 16);
        }
    #pragma unroll
    for (int mt = 0; mt < 2; ++mt) {
      float sR[4], qR[4];
      #pragma unroll
      for (int r = 0; r < 4; ++r) {
        sR[r] = u_c[0] * h1v[mt][0][r] + u_c[1] * h1v[mt][1][r];
        qR[r] = acc2[mt][0][r] * h1v[mt][0][r] + acc2[mt][1][r] * h1v[mt][1][r];
      }
      #pragma unroll
      for (int off = 1; off < 16; off <<= 1)
        #pragma unroll
        for (int r = 0; r < 4; ++r) {
          sR[r] += __shfl_xor(sR[r], off);
          qR[r] += __shfl_xor(qR[r], off);
        }
      if (n16 == 0)
        #pragma unroll
        for (int r = 0; r < 4; ++r) {
          red2[mt * 16 + q16 * 4 + r][wid * 2 + 0] = sR[r];
          red2[mt * 16 + q16 * 4 + r][wid * 2 + 1] = qR[r];
        }
    }
    __syncthreads();
    #pragma unroll
    for (int mt = 0; mt < 2; ++mt)
      #pragma unroll
      for (int r = 0; r < 4; ++r) {
        const int row = mt * 16 + q16 * 4 + r;
        const f32x4 p0 = *(const f32x4*)&red2[row][0];
        const f32x4 p1 = *(const f32x4*)&red2[row][4];
        const float s = p0[0] + p0[2] + p1[0] + p1[2];
        const float q = p0[1] + p0[3] + p1[1] + p1[3];
        const float mean = (s + sb) * (1.f / 256.f);
        const float var = fmaxf((q + sb2) * (1.f / 256.f) - mean * mean, 0.f);
        const float rs = rsqrtf(var + LN_EPS);
        haL[0] += rs * h1v[mt][0][r];
        haL[1] += rs * h1v[mt][1][r];
        if (own) { srs += rs; srm += rs * mean; }
      }
  }

  haL[0] += __shfl_xor(haL[0], 16); haL[0] += __shfl_xor(haL[0], 32);
  haL[1] += __shfl_xor(haL[1], 16); haL[1] += __shfl_xor(haL[1], 32);
  float sa = srs, sm = srm;
  sa += __shfl_xor(sa, 16); sa += __shfl_xor(sa, 32);
  sm += __shfl_xor(sm, 16); sm += __shfl_xor(sm, 32);
  if (t == 0) { srsS = sa; srmS = sm; }
  if (lane < 16) { haS[colc0] = haL[0]; haS[colc0 + 16] = haL[1]; }
  __syncthreads();
  const float srsT = srsS, srmT = srmS;
  float dot = 0.f;
  for (int k = 0; k < HID; k += 4) {
    const f32x4 w = *(const f32x4*)&w2[t * HID + k];
    const f32x4 h = *(const f32x4*)&haS[k];
    dot += w[0] * h[0] + w[1] * h[1] + w[2] * h[2] + w[3] * h[3];
  }
  const float gv = (dot + b2[t] * srsT - srmT) * (1.f / 512.f) * g2[t] + be2[t];
  gS[t] = gv;
  const int l = labels[bi];
  atomicAdd(&mgsum[(b * NSEG + l) * DIM + t], gv);
  __syncthreads();
  // ---- fused K/V row projection (was k4 proj 1/2): L2-hot wk/wv streams
  float kacc = bk[t], vacc = bv[t];
  for (int k = 0; k < DIM; k += 4) {
    const f32x4 g4 = *(const f32x4*)&gS[k];
    const f32x4 wk4 = *(const f32x4*)&wk[t * DIM + k];
    const f32x4 wv4 = *(const f32x4*)&wv[t * DIM + k];
    kacc += g4[0] * wk4[0] + g4[1] * wk4[1] + g4[2] * wk4[2] + g4[3] * wk4[3];
    vacc += g4[0] * wv4[0] + g4[1] * wv4[1] + g4[2] * wv4[2] + g4[3] * wv4[3];
  }
  Kout[bi * DIM + t] = kacc;
  Vout[bi * DIM + t] = vacc;
}

// ---------------- K5: enh + Q + attention + wo, one wave per output row, no barriers -----
// out = enh + 0.5*(bo + sum_h O_h @ wo_h^T). Each wave owns row n0+wid end-to-end; all LDS
// traffic is same-wave (compiler orders via lgkmcnt) -> zero __syncthreads, no atomics.
__global__ __launch_bounds__(256) void k5_fused(
    fpc features, const int* __restrict__ labels,
    fpc comb, fpc cntf, fpc mgsum,
    fpc K, fpc V, fpc wq, fpc bq, fpc wo, fpc bo,
    float* __restrict__ out)
{
  const int blk = blockIdx.x;          // b*128 + 4-row tile
  const int b = blk >> 7;
  const int nt = blk & 127;
  const int t = threadIdx.x;
  const int wid = t >> 6;              // wave = row
  const int l = t & 63;
  const int row = b * NPTS + nt * 4 + wid;
  __shared__ __align__(16) float E[4][256];
  __shared__ __align__(16) float Qs[4][256];
  __shared__ __align__(16) float Sx[4][512];
  __shared__ __align__(16) float OcS[4][32];

  // ---- stage enh row (same-wave)
  {
    const int lab = labels[row];
    const float cn = cntf[b * NSEG + lab];
    const int c0 = l * 4;
    const f32x4 f = *(const f32x4*)&features[row * DIM + c0];
    f32x4 v;
    if (cn >= 2.f) {
      const f32x4 ag = *(const f32x4*)&comb[(b * NSEG + lab) * DIM + c0];
      const f32x4 mg = *(const f32x4*)&mgsum[(b * NSEG + lab) * DIM + c0];
      const float rcn = 1.f / cn;
      #pragma unroll
      for (int i = 0; i < 4; ++i) v[i] = 0.7f * f[i] + 0.3f * (ag[i] + mg[i] * rcn);
    } else {
      v = f;
    }
    *(f32x4*)&E[wid][c0] = v;
  }
  // ---- Q row: lane computes cols l, l+64, l+128, l+192
  #pragma unroll
  for (int cc = 0; cc < 4; ++cc) {
    const int c = l + cc * 64;
    float q = bq[c];
    for (int k = 0; k < DIM; k += 4) {
      const f32x4 e = *(const f32x4*)&E[wid][k];
      const f32x4 w = *(const f32x4*)&wq[c * DIM + k];
      q += e[0] * w[0] + e[1] * w[1] + e[2] * w[2] + e[3] * w[3];
    }
    Qs[wid][c] = q;
  }
  float acc[4] = {0.f, 0.f, 0.f, 0.f};
  for (int h = 0; h < 8; ++h) {
    f32x4 qh[8];
    #pragma unroll
    for (int i = 0; i < 8; ++i) qh[i] = *(const f32x4*)&Qs[wid][h * 32 + i * 4];
    // scores: lane handles k = l + 64*i
    float s[8];
    #pragma unroll
    for (int i = 0; i < 8; ++i) {
      const int k = l + i * 64;
      const f32x4* kp = (const f32x4*)&K[(b * NPTS + k) * DIM + h * 32];
      float sd = 0.f;
      #pragma unroll
      for (int j = 0; j < 8; ++j) {
        const f32x4 kv = kp[j];
        sd += qh[j][0] * kv[0] + qh[j][1] * kv[1] + qh[j][2] * kv[2] + qh[j][3] * kv[3];
      }
      s[i] = sd * 0.1767766952966369f;   // 1/sqrt(32)
    }
    // wave softmax over 512 entries
    float mx = s[0];
    #pragma unroll
    for (int i = 1; i < 8; ++i) mx = fmaxf(mx, s[i]);
    #pragma unroll
    for (int off = 1; off < 64; off <<= 1) mx = fmaxf(mx, __shfl_xor(mx, off));
    float p[8], sum = 0.f;
    #pragma unroll
    for (int i = 0; i < 8; ++i) { p[i] = __expf(s[i] - mx); sum += p[i]; }
    #pragma unroll
    for (int off = 1; off < 64; off <<= 1) sum += __shfl_xor(sum, off);
    const float ri = 1.f / sum;
    #pragma unroll
    for (int i = 0; i < 8; ++i) Sx[wid][l + i * 64] = p[i] * ri;
    // PV: lane -> (j2 = (l&15)*2, k-quarter = l>>4)
    const int j2 = (l & 15) * 2;
    const int k0 = (l >> 4) * 128;
    float o0 = 0.f, o1 = 0.f;
    for (int k = k0; k < k0 + 128; ++k) {
      const float pv = Sx[wid][k];
      const float2 vv = *(const float2*)&V[(b * NPTS + k) * DIM + h * 32 + j2];
      o0 += pv * vv.x; o1 += pv * vv.y;
    }
    o0 += __shfl_xor(o0, 16); o1 += __shfl_xor(o1, 16);
    o0 += __shfl_xor(o0, 32); o1 += __shfl_xor(o1, 32);
    if (l < 16) { OcS[wid][j2] = o0; OcS[wid][j2 + 1] = o1; }
    // wo accumulate (same-wave OcS read)
    #pragma unroll
    for (int cc = 0; cc < 4; ++cc) {
      const int c = l + cc * 64;
      fpc wr = &wo[c * DIM + h * 32];
      float d = 0.f;
      #pragma unroll
      for (int j = 0; j < 32; j += 4) {
        const f32x4 w = *(const f32x4*)&wr[j];
        const f32x4 oc = *(const f32x4*)&OcS[wid][j];
        d += w[0] * oc[0] + w[1] * oc[1] + w[2] * oc[2] + w[3] * oc[3];
      }
      acc[cc] += d;
    }
  }
  // ---- epilogue
  #pragma unroll
  for (int cc = 0; cc < 4; ++cc) {
    const int c = l + cc * 64;
    out[row * DIM + c] = E[wid][c] + 0.5f * (acc[cc] + bo[c]);
  }
}

extern "C" void kernel_launch(void* const* d_in, const int* in_sizes, int n_in,
                              void* d_out, int out_size, void* d_ws, size_t ws_size,
                              hipStream_t stream)
{
  fpc coords  = (fpc)d_in[0];
  fpc features= (fpc)d_in[1];
  const int* labels = (const int*)d_in[2];
  fpc ge_w1 = (fpc)d_in[3],  ge_b1 = (fpc)d_in[4],  ge_g1 = (fpc)d_in[5],  ge_be1 = (fpc)d_in[6];
  fpc ge_w2 = (fpc)d_in[7],  ge_b2 = (fpc)d_in[8],  ge_g2 = (fpc)d_in[9],  ge_be2 = (fpc)d_in[10];
  fpc ag_w1 = (fpc)d_in[11], ag_b1 = (fpc)d_in[12], ag_g1 = (fpc)d_in[13], ag_be1 = (fpc)d_in[14];
  fpc ag_w2 = (fpc)d_in[15], ag_b2 = (fpc)d_in[16], ag_g2 = (fpc)d_in[17], ag_be2 = (fpc)d_in[18];
  fpc wq = (fpc)d_in[19], bq = (fpc)d_in[20];
  fpc wk = (fpc)d_in[21], bk = (fpc)d_in[22];
  fpc wv = (fpc)d_in[23], bv = (fpc)d_in[24];
  fpc wo = (fpc)d_in[25], bo = (fpc)d_in[26];

  float* ws = (float*)d_ws;
  float* comb    = ws;                    // 32768
  float* cntf    = comb + 32768;          // 128
  float* Kb      = cntf + 128;            // 262144
  float* Vb      = Kb + 262144;           // 262144
  float* mgsum   = Vb + 262144;           // 32768
  float* gmwF    = mgsum + 32768;         // 8192 floats (128x128 bf16)
  float* uw      = gmwF + 8192;           // 128
  float* tvw     = uw + 128;              // 128
  float* scw     = tvw + 128;             // 8
  float* qfw     = scw + 8;               // 128

  k02_prep_agg<<<258, 256, 0, stream>>>(ge_w1, ge_b1, ge_w2, ge_b2,
                                        features, labels,
                                        ag_w1, ag_b1, ag_g1, ag_be1,
                                        ag_w2, ag_b2, ag_g2, ag_be2,
                                        (unsigned short*)gmwF, uw, tvw, scw, qfw,
                                        comb, cntf, mgsum);
  k1_geo<<<1024, 256, 0, stream>>>(coords, labels, ge_g1, ge_be1, ge_w1, ge_b1,
                                   ge_w2, ge_b2, ge_g2, ge_be2,
                                   wk, bk, wv, bv,
                                   (const unsigned short*)gmwF, uw, tvw, scw, qfw,
                                   Kb, Vb, mgsum);
  k5_fused<<<256, 256, 0, stream>>>(features, labels, comb, cntf, mgsum,
                                    Kb, Vb, wq, bq, wo, bo, (float*)d_out);
}

// Round 7
// 432.731 us; speedup vs baseline: 1.2217x; 1.2217x over previous
//
#include <hip/hip_runtime.h>

#define NPTS 512
#define DIM  256
#define HID  128
#define NSEG 64
#define LN_EPS 1e-5f

typedef short s16x4 __attribute__((ext_vector_type(4)));
typedef short s16x8 __attribute__((ext_vector_type(8)));
typedef float f32x4 __attribute__((ext_vector_type(4)));
typedef const float* fpc;

__device__ __forceinline__ unsigned short f2bf(float f) {
  unsigned int u = __builtin_bit_cast(unsigned int, f);
  u += 0x7FFFu + ((u >> 16) & 1u);
  return (unsigned short)(u >> 16);
}

// ---------------- K02: prep + wk/wv transpose + aggregator + mgsum zero ------------------
// blocks 0..129 prep; 130..145 transpose (8 per matrix, LDS-tiled, coalesced reads);
// 146..273 aggregator. Transpose enables coalesced K/V epilogue in k1 (v9 lesson: per-
// thread-row weight reads = 64 lines/instr @25% -> +106us on k1).
__global__ void k02_prep_agg(
    fpc ge_w1, fpc ge_b1, fpc ge_w2, fpc ge_b2,
    fpc features, const int* __restrict__ labels,
    fpc wk, fpc wv,
    fpc ag_w1, fpc ag_b1, fpc ag_g1, fpc ag_be1,
    fpc ag_w2, fpc ag_b2, fpc ag_g2, fpc ag_be2,
    unsigned short* __restrict__ gmw, float* __restrict__ uw,
    float* __restrict__ tvw, float* __restrict__ scw, float* __restrict__ qfw,
    float* __restrict__ wkT, float* __restrict__ wvT,
    float* __restrict__ comb, float* __restrict__ cntf, float* __restrict__ mgsum)
{
  const int blk = blockIdx.x;
  const int t = threadIdx.x;
  if (blk < 130) {                       // ---- prep (t<128 active)
    if (t < 128) {
      if (blk < 128) {
        const int c = blk;
        float acc = 0.f;
        for (int d = 0; d < DIM; ++d) acc += ge_w2[d * HID + c] * ge_w2[d * HID + t];
        gmw[c * HID + t] = f2bf(acc);
      } else if (blk == 128) {
        float uu = 0.f, tv = 0.f;
        for (int d = 0; d < DIM; ++d) { const float w = ge_w2[d * HID + t]; uu += w; tv += ge_b2[d] * w; }
        uw[t] = uu; tvw[t] = tv;
        if (t == 0) {
          float s = 0.f, s2 = 0.f;
          for (int d = 0; d < DIM; ++d) { const float bb = ge_b2[d]; s += bb; s2 += bb * bb; }
          scw[0] = s; scw[1] = s2;
        }
      } else {
        if (t < 101) {
          float acc = 0.f;
          if (t < 81) {
            const int a = t / 9, c = t % 9;
            for (int h = 0; h < HID; ++h) acc += ge_w1[h * 9 + a] * ge_w1[h * 9 + c];
            qfw[a * 12 + c] = acc;
          } else if (t < 90) {
            const int a = t - 81;
            for (int h = 0; h < HID; ++h) acc += ge_w1[h * 9 + a];
            qfw[108 + a] = acc;
          } else if (t < 99) {
            const int a = t - 90;
            for (int h = 0; h < HID; ++h) acc += ge_b1[h] * ge_w1[h * 9 + a];
            qfw[117 + a] = acc;
          } else if (t == 99) {
            float acc2 = 0.f;
            for (int h = 0; h < HID; ++h) acc2 += ge_b1[h];
            qfw[126] = acc2;
          } else {
            float acc2 = 0.f;
            for (int h = 0; h < HID; ++h) acc2 += ge_b1[h] * ge_b1[h];
            qfw[127] = acc2;
          }
        }
      }
    }
    return;
  }
  if (blk < 146) {                       // ---- transpose wk/wv -> wkT/wvT
    __shared__ __align__(16) float T[32][256];
    const int tr = blk - 130;
    fpc src = (tr < 8) ? wk : wv;
    float* dst = (tr < 8) ? wkT : wvT;
    const int c0 = (tr & 7) * 32;        // source row range (output-channel dim)
    for (int i = 0; i < 32; ++i) T[i][t] = src[(c0 + i) * DIM + t];   // coalesced reads
    __syncthreads();
    #pragma unroll
    for (int j4 = 0; j4 < 32; j4 += 4) {
      f32x4 v;
      v[0] = T[j4 + 0][t]; v[1] = T[j4 + 1][t];
      v[2] = T[j4 + 2][t]; v[3] = T[j4 + 3][t];
      *(f32x4*)&dst[t * DIM + c0 + j4] = v;   // dst[k=t][c] = src[c][k]
    }
    return;
  }
  // ---- aggregator (mg-free) + mgsum zero
  const int item = blk - 146;
  const int lane = t & 63;
  const int wid = t >> 6;
  const int b = item >> 6;
  const int s = item & 63;
  __shared__ __align__(16) int labS[NPTS];
  __shared__ __align__(16) float mfS[DIM];
  __shared__ __align__(16) float h1S[HID];
  __shared__ __align__(16) float red[8];
  mgsum[(b * NSEG + s) * DIM + t] = 0.f;
  for (int n = t; n < NPTS; n += 256) labS[n] = labels[b * NPTS + n];
  __syncthreads();
  float accf = 0.f;
  int cnt = 0;
  for (int n = 0; n < NPTS; n += 4) {
    const int4 l4 = *(const int4*)&labS[n];
    if (l4.x == s) { cnt++; accf += features[(b * NPTS + n + 0) * DIM + t]; }
    if (l4.y == s) { cnt++; accf += features[(b * NPTS + n + 1) * DIM + t]; }
    if (l4.z == s) { cnt++; accf += features[(b * NPTS + n + 2) * DIM + t]; }
    if (l4.w == s) { cnt++; accf += features[(b * NPTS + n + 3) * DIM + t]; }
  }
  const float denom = fmaxf((float)cnt, 1.f);
  mfS[t] = accf / denom;
  __syncthreads();
  float hval = 0.f;
  if (t < HID) {
    float o = ag_b1[t];
    for (int k = 0; k < DIM; k += 4) {
      const f32x4 x = *(const f32x4*)&mfS[k];
      const f32x4 w = *(const f32x4*)&ag_w1[t * DIM + k];
      o += x[0] * w[0] + x[1] * w[1] + x[2] * w[2] + x[3] * w[3];
    }
    hval = o;
  }
  float sv = (t < HID) ? hval : 0.f;
  float qv = (t < HID) ? hval * hval : 0.f;
  #pragma unroll
  for (int off = 1; off < 64; off <<= 1) { sv += __shfl_xor(sv, off); qv += __shfl_xor(qv, off); }
  if (lane == 0 && wid < 2) { red[wid * 2] = sv; red[wid * 2 + 1] = qv; }
  __syncthreads();
  if (t < HID) {
    const float s1 = red[0] + red[2], q1 = red[1] + red[3];
    const float mean = s1 * (1.f / 128.f);
    const float var = fmaxf(q1 * (1.f / 128.f) - mean * mean, 0.f);
    const float rs = rsqrtf(var + LN_EPS);
    h1S[t] = fmaxf((hval - mean) * rs * ag_g1[t] + ag_be1[t], 0.f);
  }
  __syncthreads();
  float o = ag_b2[t];
  for (int k = 0; k < HID; k += 4) {
    const f32x4 x = *(const f32x4*)&h1S[k];
    const f32x4 w = *(const f32x4*)&ag_w2[t * HID + k];
    o += x[0] * w[0] + x[1] * w[1] + x[2] * w[2] + x[3] * w[3];
  }
  float sv2 = o, qv2 = o * o;
  #pragma unroll
  for (int off = 1; off < 64; off <<= 1) { sv2 += __shfl_xor(sv2, off); qv2 += __shfl_xor(qv2, off); }
  if (lane == 0) { red[wid * 2] = sv2; red[wid * 2 + 1] = qv2; }
  __syncthreads();
  const float sa = red[0] + red[2] + red[4] + red[6];
  const float qa = red[1] + red[3] + red[5] + red[7];
  const float mean = sa * (1.f / 256.f);
  const float var = fmaxf(qa * (1.f / 256.f) - mean * mean, 0.f);
  const float rs = rsqrtf(var + LN_EPS);
  comb[(b * NSEG + s) * DIM + t] = (o - mean) * rs * ag_g2[t] + ag_be2[t];
  if (t == 0) cntf[b * NSEG + s] = (float)cnt;
}

// ---------------- K1: v6 core + mgsum atomics + COALESCED K/V epilogue (wkT/wvT) ---------
__global__ __launch_bounds__(256, 4) void k1_geo(
    fpc coords, const int* __restrict__ labels,
    fpc g1, fpc be1, fpc w1, fpc b1,
    fpc w2, fpc b2, fpc g2, fpc be2,
    fpc wkT, fpc bk, fpc wvT, fpc bv,
    const unsigned short* __restrict__ gmw, fpc uw, fpc tvw, fpc scw, fpc qfw,
    float* __restrict__ Kout, float* __restrict__ Vout, float* __restrict__ mgsum)
{
  const int t = threadIdx.x;
  const int lane = t & 63;
  const int wid = t >> 6;
  const int bi = blockIdx.x;           // b*512 + i
  const int b = bi >> 9;

  __shared__ __align__(16) float xs[NPTS][8];
  __shared__ __align__(16) float st[NPTS][2];
  __shared__ __align__(16) float qf[128];
  __shared__ __align__(16) unsigned short h1s[32][136];
  __shared__ __align__(16) float red2[32][12];
  __shared__ __align__(16) float haS[128];
  __shared__ __align__(16) float gS[256];
  __shared__ float srsS, srmS;

  if (t < 128) qf[t] = qfw[t];

  float w1r[2][7], b1r[2], g1r[2], be1r[2];
  #pragma unroll
  for (int r = 0; r < 2; ++r) {
    const int hh = lane * 2 + r;
    w1r[r][0] = w1[hh * 9 + 0]; w1r[r][1] = w1[hh * 9 + 1];
    w1r[r][2] = w1[hh * 9 + 2]; w1r[r][3] = w1[hh * 9 + 3];
    w1r[r][4] = w1[hh * 9 + 6]; w1r[r][5] = w1[hh * 9 + 7];
    w1r[r][6] = w1[hh * 9 + 8];
    b1r[r] = b1[hh]; g1r[r] = g1[hh]; be1r[r] = be1[hh];
  }
  const int n16 = lane & 15;
  const int q16 = lane >> 4;
  const int colc0 = wid * 32 + n16;
  s16x8 gfrag[2][4];
  float u_c[2], tv_c[2];
  #pragma unroll
  for (int dt = 0; dt < 2; ++dt) {
    const int c = colc0 + dt * 16;
    u_c[dt] = uw[c];
    tv_c[dt] = 2.f * tvw[c];
    #pragma unroll
    for (int kt = 0; kt < 4; ++kt)
      gfrag[dt][kt] = *(const s16x8*)&gmw[c * HID + kt * 32 + q16 * 8];
  }
  const float sb = scw[0], sb2 = scw[1];
  const float cix = coords[bi * 3 + 0];
  const float ciy = coords[bi * 3 + 1];
  const float ciz = coords[bi * 3 + 2];
  __syncthreads();

  #pragma unroll
  for (int jj = 0; jj < 2; ++jj) {
    const int j = t + jj * 256;
    const float cjx = coords[(b * NPTS + j) * 3 + 0];
    const float cjy = coords[(b * NPTS + j) * 3 + 1];
    const float cjz = coords[(b * NPTS + j) * 3 + 2];
    const float rx = cix - cjx, ry = ciy - cjy, rz = ciz - cjz;
    const float dist = sqrtf(rx * rx + ry * ry + rz * rz);
    const float inv = 1.f / fmaxf(dist, 1e-12f);
    const float r0 = rx * inv, r1 = ry * inv, r2 = rz * inv;
    const float x0 = dist, x1 = r0, x2 = r1, x3 = r2;
    const float x6 = r1 * r2, x7 = r0 * r1, x8 = r0 * r2;
    float S1 = qf[126] + qf[108] * x0 + qf[109] * x1 + qf[110] * x2 + qf[111] * x3
             + qf[114] * x6 + qf[115] * x7 + qf[116] * x8;
    float tx = qf[117] * x0 + qf[118] * x1 + qf[119] * x2 + qf[120] * x3
             + qf[123] * x6 + qf[124] * x7 + qf[125] * x8;
    const float xv[9] = {x0, x1, x2, x3, 0.f, 0.f, x6, x7, x8};
    float quad = 0.f;
    #pragma unroll
    for (int a = 0; a < 9; ++a) {
      if (a == 4 || a == 5) continue;
      const f32x4 q0 = *(const f32x4*)&qf[a * 12];
      const f32x4 q1 = *(const f32x4*)&qf[a * 12 + 4];
      const f32x4 q2 = *(const f32x4*)&qf[a * 12 + 8];
      const float ya = q0[0] * x0 + q0[1] * x1 + q0[2] * x2 + q0[3] * x3
                     + q1[2] * x6 + q1[3] * x7 + q2[0] * x8;
      quad += ya * xv[a];
    }
    const float S2 = quad + 2.f * tx + qf[127];
    const float mean = S1 * (1.f / 128.f);
    const float var = fmaxf(S2 * (1.f / 128.f) - mean * mean, 0.f);
    st[j][0] = mean;
    st[j][1] = rsqrtf(var + LN_EPS);
    f32x4 X0; X0[0] = x0; X0[1] = x1; X0[2] = x2; X0[3] = x3;
    f32x4 X1; X1[0] = x6; X1[1] = x7; X1[2] = x8; X1[3] = 0.f;
    *(f32x4*)&xs[j][0] = X0;
    *(f32x4*)&xs[j][4] = X1;
  }
  __syncthreads();

  float haL[2] = {0.f, 0.f};
  float srs = 0.f, srm = 0.f;
  const bool own = (wid == 0) && (n16 == 0);

  for (int jb = 0; jb < NPTS; jb += 32) {
    #pragma unroll
    for (int sr = 0; sr < 8; ++sr) {
      const int m = sr * 4 + wid;
      const int j = jb + m;
      const f32x4 X0 = *(const f32x4*)&xs[j][0];
      const f32x4 X1 = *(const f32x4*)&xs[j][4];
      const float2 ms = *(const float2*)&st[j][0];
      unsigned int pk = 0;
      #pragma unroll
      for (int r = 0; r < 2; ++r) {
        const float a = b1r[r]
          + X0[0] * w1r[r][0] + X0[1] * w1r[r][1] + X0[2] * w1r[r][2] + X0[3] * w1r[r][3]
          + X1[0] * w1r[r][4] + X1[1] * w1r[r][5] + X1[2] * w1r[r][6];
        const float e = (a - ms.x) * ms.y * g1r[r] + be1r[r];
        pk |= ((unsigned int)f2bf(fmaxf(e, 0.f))) << (16 * r);
      }
      *(unsigned int*)&h1s[m][lane * 2] = pk;
    }
    __syncthreads();
    f32x4 acc2[2][2];
    #pragma unroll
    for (int mt = 0; mt < 2; ++mt)
      #pragma unroll
      for (int dt = 0; dt < 2; ++dt) {
        f32x4 z; z[0] = tv_c[dt]; z[1] = tv_c[dt]; z[2] = tv_c[dt]; z[3] = tv_c[dt];
        acc2[mt][dt] = z;
      }
    #pragma unroll
    for (int mt = 0; mt < 2; ++mt)
      #pragma unroll
      for (int kt = 0; kt < 4; ++kt) {
        const s16x8 af = *(const s16x8*)&h1s[mt * 16 + n16][kt * 32 + q16 * 8];
        #pragma unroll
        for (int dt = 0; dt < 2; ++dt)
          acc2[mt][dt] = __builtin_amdgcn_mfma_f32_16x16x32_bf16(af, gfrag[dt][kt], acc2[mt][dt], 0, 0, 0);
      }
    float h1v[2][2][4];
    #pragma unroll
    for (int mt = 0; mt < 2; ++mt)
      #pragma unroll
      for (int dt = 0; dt < 2; ++dt)
        #pragma unroll
        for (int r = 0; r < 4; ++r) {
          const unsigned short hv = h1s[mt * 16 + q16 * 4 + r][colc0 + dt * 16];
          h1v[mt][dt][r] = __builtin_bit_cast(float, ((unsigned int)hv) << 16);
        }
    #pragma unroll
    for (int mt = 0; mt < 2; ++mt) {
      float sR[4], qR[4];
      #pragma unroll
      for (int r = 0; r < 4; ++r) {
        sR[r] = u_c[0] * h1v[mt][0][r] + u_c[1] * h1v[mt][1][r];
        qR[r] = acc2[mt][0][r] * h1v[mt][0][r] + acc2[mt][1][r] * h1v[mt][1][r];
      }
      #pragma unroll
      for (int off = 1; off < 16; off <<= 1)
        #pragma unroll
        for (int r = 0; r < 4; ++r) {
          sR[r] += __shfl_xor(sR[r], off);
          qR[r] += __shfl_xor(qR[r], off);
        }
      if (n16 == 0)
        #pragma unroll
        for (int r = 0; r < 4; ++r) {
          red2[mt * 16 + q16 * 4 + r][wid * 2 + 0] = sR[r];
          red2[mt * 16 + q16 * 4 + r][wid * 2 + 1] = qR[r];
        }
    }
    __syncthreads();
    #pragma unroll
    for (int mt = 0; mt < 2; ++mt)
      #pragma unroll
      for (int r = 0; r < 4; ++r) {
        const int row = mt * 16 + q16 * 4 + r;
        const f32x4 p0 = *(const f32x4*)&red2[row][0];
        const f32x4 p1 = *(const f32x4*)&red2[row][4];
        const float s = p0[0] + p0[2] + p1[0] + p1[2];
        const float q = p0[1] + p0[3] + p1[1] + p1[3];
        const float mean = (s + sb) * (1.f / 256.f);
        const float var = fmaxf((q + sb2) * (1.f / 256.f) - mean * mean, 0.f);
        const float rs = rsqrtf(var + LN_EPS);
        haL[0] += rs * h1v[mt][0][r];
        haL[1] += rs * h1v[mt][1][r];
        if (own) { srs += rs; srm += rs * mean; }
      }
  }

  haL[0] += __shfl_xor(haL[0], 16); haL[0] += __shfl_xor(haL[0], 32);
  haL[1] += __shfl_xor(haL[1], 16); haL[1] += __shfl_xor(haL[1], 32);
  float sa = srs, sm = srm;
  sa += __shfl_xor(sa, 16); sa += __shfl_xor(sa, 32);
  sm += __shfl_xor(sm, 16); sm += __shfl_xor(sm, 32);
  if (t == 0) { srsS = sa; srmS = sm; }
  if (lane < 16) { haS[colc0] = haL[0]; haS[colc0 + 16] = haL[1]; }
  __syncthreads();
  const float srsT = srsS, srmT = srmS;
  float dot = 0.f;
  for (int k = 0; k < HID; k += 4) {
    const f32x4 w = *(const f32x4*)&w2[t * HID + k];
    const f32x4 h = *(const f32x4*)&haS[k];
    dot += w[0] * h[0] + w[1] * h[1] + w[2] * h[2] + w[3] * h[3];
  }
  const float gv = (dot + b2[t] * srsT - srmT) * (1.f / 512.f) * g2[t] + be2[t];
  gS[t] = gv;
  const int l = labels[bi];
  atomicAdd(&mgsum[(b * NSEG + l) * DIM + t], gv);
  __syncthreads();
  // ---- K/V rows via TRANSPOSED weights: lane-consecutive loads, full line use
  float kacc = bk[t], vacc = bv[t];
  for (int k = 0; k < DIM; k += 4) {
    const f32x4 g4 = *(const f32x4*)&gS[k];
    kacc += g4[0] * wkT[(k + 0) * DIM + t] + g4[1] * wkT[(k + 1) * DIM + t]
          + g4[2] * wkT[(k + 2) * DIM + t] + g4[3] * wkT[(k + 3) * DIM + t];
    vacc += g4[0] * wvT[(k + 0) * DIM + t] + g4[1] * wvT[(k + 1) * DIM + t]
          + g4[2] * wvT[(k + 2) * DIM + t] + g4[3] * wvT[(k + 3) * DIM + t];
  }
  Kout[bi * DIM + t] = kacc;
  Vout[bi * DIM + t] = vacc;
}

// ---------------- K5 v2: 2 rows/block, wave = (row, 4-head half) — 4x v9's TLP -----------
// v9 lesson: 256 blocks x 4 waves = 1 wave/SIMD, latency fully exposed (~165us). v10:
// 512 blocks x 4 waves = 2 blocks/CU = 2 waves/SIMD, half per-wave work. Two barriers.
__global__ __launch_bounds__(256) void k5_fused(
    fpc features, const int* __restrict__ labels,
    fpc comb, fpc cntf, fpc mgsum,
    fpc K, fpc V, fpc wq, fpc bq, fpc wo, fpc bo,
    float* __restrict__ out)
{
  const int blk = blockIdx.x;          // b*256 + 2-row tile
  const int b = blk >> 8;
  const int nt = blk & 255;
  const int t = threadIdx.x;
  const int wid = t >> 6;
  const int l = t & 63;
  const int rowL = wid >> 1;           // 0..1
  const int hh = (wid & 1) * 4;        // this wave's head base
  __shared__ __align__(16) float E[2][256];
  __shared__ __align__(16) float Qs[2][256];
  __shared__ __align__(16) float Px[4][512];
  __shared__ __align__(16) float OcS[2][256];

  // ---- stage enh for both rows (threads 0..127)
  if (t < 128) {
    const int r = t >> 6, c4 = (t & 63) * 4;
    const int rg = b * NPTS + nt * 2 + r;
    const int lab = labels[rg];
    const float cn = cntf[b * NSEG + lab];
    const f32x4 f = *(const f32x4*)&features[rg * DIM + c4];
    f32x4 v;
    if (cn >= 2.f) {
      const f32x4 ag = *(const f32x4*)&comb[(b * NSEG + lab) * DIM + c4];
      const f32x4 mg = *(const f32x4*)&mgsum[(b * NSEG + lab) * DIM + c4];
      const float rcn = 1.f / cn;
      #pragma unroll
      for (int i = 0; i < 4; ++i) v[i] = 0.7f * f[i] + 0.3f * (ag[i] + mg[i] * rcn);
    } else {
      v = f;
    }
    *(f32x4*)&E[r][c4] = v;
  }
  __syncthreads();
  // ---- Q slice for this wave's 4 heads (cols hh*32 .. hh*32+127), same-wave LDS
  #pragma unroll
  for (int cc = 0; cc < 2; ++cc) {
    const int c = hh * 32 + cc * 64 + l;
    float q = bq[c];
    for (int k = 0; k < DIM; k += 4) {
      const f32x4 e = *(const f32x4*)&E[rowL][k];
      const f32x4 w = *(const f32x4*)&wq[c * DIM + k];
      q += e[0] * w[0] + e[1] * w[1] + e[2] * w[2] + e[3] * w[3];
    }
    Qs[rowL][c] = q;
  }
  // ---- per-head: scores -> wave softmax -> PV -> OcS
  for (int hi = 0; hi < 4; ++hi) {
    const int h = hh + hi;
    f32x4 qh[8];
    #pragma unroll
    for (int i = 0; i < 8; ++i) qh[i] = *(const f32x4*)&Qs[rowL][h * 32 + i * 4];
    float s[8];
    #pragma unroll
    for (int i = 0; i < 8; ++i) {
      const int k = l + i * 64;
      const f32x4* kp = (const f32x4*)&K[(b * NPTS + k) * DIM + h * 32];
      float sd = 0.f;
      #pragma unroll
      for (int j = 0; j < 8; ++j) {
        const f32x4 kv = kp[j];
        sd += qh[j][0] * kv[0] + qh[j][1] * kv[1] + qh[j][2] * kv[2] + qh[j][3] * kv[3];
      }
      s[i] = sd * 0.1767766952966369f;   // 1/sqrt(32)
    }
    float mx = s[0];
    #pragma unroll
    for (int i = 1; i < 8; ++i) mx = fmaxf(mx, s[i]);
    #pragma unroll
    for (int off = 1; off < 64; off <<= 1) mx = fmaxf(mx, __shfl_xor(mx, off));
    float p[8], sum = 0.f;
    #pragma unroll
    for (int i = 0; i < 8; ++i) { p[i] = __expf(s[i] - mx); sum += p[i]; }
    #pragma unroll
    for (int off = 1; off < 64; off <<= 1) sum += __shfl_xor(sum, off);
    const float ri = 1.f / sum;
    #pragma unroll
    for (int i = 0; i < 8; ++i) Px[wid][l + i * 64] = p[i] * ri;
    const int j2 = (l & 15) * 2;
    const int k0 = (l >> 4) * 128;
    float o0 = 0.f, o1 = 0.f;
    for (int k = k0; k < k0 + 128; ++k) {
      const float pv = Px[wid][k];
      const float2 vv = *(const float2*)&V[(b * NPTS + k) * DIM + h * 32 + j2];
      o0 += pv * vv.x; o1 += pv * vv.y;
    }
    o0 += __shfl_xor(o0, 16); o1 += __shfl_xor(o1, 16);
    o0 += __shfl_xor(o0, 32); o1 += __shfl_xor(o1, 32);
    if (l < 16) { OcS[rowL][h * 32 + j2] = o0; OcS[rowL][h * 32 + j2 + 1] = o1; }
  }
  __syncthreads();
  // ---- wo projection + epilogue: thread -> (row = t>>7, 2 cols)
  const int r2 = t >> 7;
  const int rg2 = b * NPTS + nt * 2 + r2;
  #pragma unroll
  for (int cc = 0; cc < 2; ++cc) {
    const int c = (t & 127) + cc * 128;
    float d = 0.f;
    for (int j = 0; j < DIM; j += 4) {
      const f32x4 w = *(const f32x4*)&wo[c * DIM + j];
      const f32x4 oc = *(const f32x4*)&OcS[r2][j];
      d += w[0] * oc[0] + w[1] * oc[1] + w[2] * oc[2] + w[3] * oc[3];
    }
    out[rg2 * DIM + c] = E[r2][c] + 0.5f * (d + bo[c]);
  }
}

extern "C" void kernel_launch(void* const* d_in, const int* in_sizes, int n_in,
                              void* d_out, int out_size, void* d_ws, size_t ws_size,
                              hipStream_t stream)
{
  fpc coords  = (fpc)d_in[0];
  fpc features= (fpc)d_in[1];
  const int* labels = (const int*)d_in[2];
  fpc ge_w1 = (fpc)d_in[3],  ge_b1 = (fpc)d_in[4],  ge_g1 = (fpc)d_in[5],  ge_be1 = (fpc)d_in[6];
  fpc ge_w2 = (fpc)d_in[7],  ge_b2 = (fpc)d_in[8],  ge_g2 = (fpc)d_in[9],  ge_be2 = (fpc)d_in[10];
  fpc ag_w1 = (fpc)d_in[11], ag_b1 = (fpc)d_in[12], ag_g1 = (fpc)d_in[13], ag_be1 = (fpc)d_in[14];
  fpc ag_w2 = (fpc)d_in[15], ag_b2 = (fpc)d_in[16], ag_g2 = (fpc)d_in[17], ag_be2 = (fpc)d_in[18];
  fpc wq = (fpc)d_in[19], bq = (fpc)d_in[20];
  fpc wk = (fpc)d_in[21], bk = (fpc)d_in[22];
  fpc wv = (fpc)d_in[23], bv = (fpc)d_in[24];
  fpc wo = (fpc)d_in[25], bo = (fpc)d_in[26];

  float* ws = (float*)d_ws;
  float* comb    = ws;                    // 32768
  float* cntf    = comb + 32768;          // 128
  float* Kb      = cntf + 128;            // 262144
  float* Vb      = Kb + 262144;           // 262144
  float* mgsum   = Vb + 262144;           // 32768
  float* gmwF    = mgsum + 32768;         // 8192 floats (128x128 bf16)
  float* uw      = gmwF + 8192;           // 128
  float* tvw     = uw + 128;              // 128
  float* scw     = tvw + 128;             // 8
  float* qfw     = scw + 8;               // 128
  float* wkT     = qfw + 128;             // 65536
  float* wvT     = wkT + 65536;           // 65536

  k02_prep_agg<<<274, 256, 0, stream>>>(ge_w1, ge_b1, ge_w2, ge_b2,
                                        features, labels, wk, wv,
                                        ag_w1, ag_b1, ag_g1, ag_be1,
                                        ag_w2, ag_b2, ag_g2, ag_be2,
                                        (unsigned short*)gmwF, uw, tvw, scw, qfw,
                                        wkT, wvT, comb, cntf, mgsum);
  k1_geo<<<1024, 256, 0, stream>>>(coords, labels, ge_g1, ge_be1, ge_w1, ge_b1,
                                   ge_w2, ge_b2, ge_g2, ge_be2,
                                   wkT, bk, wvT, bv,
                                   (const unsigned short*)gmwF, uw, tvw, scw, qfw,
                                   Kb, Vb, mgsum);
  k5_fused<<<512, 256, 0, stream>>>(features, labels, comb, cntf, mgsum,
                                    Kb, Vb, wq, bq, wo, bo, (float*)d_out);
}

// Round 8
// 323.896 us; speedup vs baseline: 1.6322x; 1.3360x over previous
//
#include <hip/hip_runtime.h>

#define NPTS 512
#define DIM  256
#define HID  128
#define NSEG 64
#define LN_EPS 1e-5f
#define KTS 520   // Kt row stride (floats): breaks 2KB power-of-2 channel aliasing

typedef short s16x4 __attribute__((ext_vector_type(4)));
typedef short s16x8 __attribute__((ext_vector_type(8)));
typedef float f32x4 __attribute__((ext_vector_type(4)));
typedef const float* fpc;

__device__ __forceinline__ unsigned short f2bf(float f) {
  unsigned int u = __builtin_bit_cast(unsigned int, f);
  u += 0x7FFFu + ((u >> 16) & 1u);
  return (unsigned short)(u >> 16);
}

// ---------------- K02: prep + transposes (wk,wv,wq,wo) + aggregator + mgsum zero ---------
__global__ void k02_prep_agg(
    fpc ge_w1, fpc ge_b1, fpc ge_w2, fpc ge_b2,
    fpc features, const int* __restrict__ labels,
    fpc wk, fpc wv, fpc wq, fpc wo,
    fpc ag_w1, fpc ag_b1, fpc ag_g1, fpc ag_be1,
    fpc ag_w2, fpc ag_b2, fpc ag_g2, fpc ag_be2,
    unsigned short* __restrict__ gmw, float* __restrict__ uw,
    float* __restrict__ tvw, float* __restrict__ scw, float* __restrict__ qfw,
    float* __restrict__ wkT, float* __restrict__ wvT,
    float* __restrict__ wqT, float* __restrict__ woT,
    float* __restrict__ comb, float* __restrict__ cntf, float* __restrict__ mgsum)
{
  const int blk = blockIdx.x;
  const int t = threadIdx.x;
  if (blk < 130) {                       // ---- prep (t<128 active)
    if (t < 128) {
      if (blk < 128) {
        const int c = blk;
        float acc = 0.f;
        for (int d = 0; d < DIM; ++d) acc += ge_w2[d * HID + c] * ge_w2[d * HID + t];
        gmw[c * HID + t] = f2bf(acc);
      } else if (blk == 128) {
        float uu = 0.f, tv = 0.f;
        for (int d = 0; d < DIM; ++d) { const float w = ge_w2[d * HID + t]; uu += w; tv += ge_b2[d] * w; }
        uw[t] = uu; tvw[t] = tv;
        if (t == 0) {
          float s = 0.f, s2 = 0.f;
          for (int d = 0; d < DIM; ++d) { const float bb = ge_b2[d]; s += bb; s2 += bb * bb; }
          scw[0] = s; scw[1] = s2;
        }
      } else {
        if (t < 101) {
          float acc = 0.f;
          if (t < 81) {
            const int a = t / 9, c = t % 9;
            for (int h = 0; h < HID; ++h) acc += ge_w1[h * 9 + a] * ge_w1[h * 9 + c];
            qfw[a * 12 + c] = acc;
          } else if (t < 90) {
            const int a = t - 81;
            for (int h = 0; h < HID; ++h) acc += ge_w1[h * 9 + a];
            qfw[108 + a] = acc;
          } else if (t < 99) {
            const int a = t - 90;
            for (int h = 0; h < HID; ++h) acc += ge_b1[h] * ge_w1[h * 9 + a];
            qfw[117 + a] = acc;
          } else if (t == 99) {
            float acc2 = 0.f;
            for (int h = 0; h < HID; ++h) acc2 += ge_b1[h];
            qfw[126] = acc2;
          } else {
            float acc2 = 0.f;
            for (int h = 0; h < HID; ++h) acc2 += ge_b1[h] * ge_b1[h];
            qfw[127] = acc2;
          }
        }
      }
    }
    return;
  }
  if (blk < 162) {                       // ---- transpose 4 matrices x 8 col-strips
    __shared__ __align__(16) float T[32][256];
    const int tr = blk - 130;
    const int m = tr >> 3;
    fpc src = (m == 0) ? wk : (m == 1) ? wv : (m == 2) ? wq : wo;
    float* dst = (m == 0) ? wkT : (m == 1) ? wvT : (m == 2) ? wqT : woT;
    const int c0 = (tr & 7) * 32;
    for (int i = 0; i < 32; ++i) T[i][t] = src[(c0 + i) * DIM + t];   // coalesced reads
    __syncthreads();
    #pragma unroll
    for (int j4 = 0; j4 < 32; j4 += 4) {
      f32x4 v;
      v[0] = T[j4 + 0][t]; v[1] = T[j4 + 1][t];
      v[2] = T[j4 + 2][t]; v[3] = T[j4 + 3][t];
      *(f32x4*)&dst[t * DIM + c0 + j4] = v;   // dst[k=t][c] = src[c][k]
    }
    return;
  }
  // ---- aggregator (mg-free) + mgsum zero
  const int item = blk - 162;
  const int lane = t & 63;
  const int wid = t >> 6;
  const int b = item >> 6;
  const int s = item & 63;
  __shared__ __align__(16) int labS[NPTS];
  __shared__ __align__(16) float mfS[DIM];
  __shared__ __align__(16) float h1S[HID];
  __shared__ __align__(16) float red[8];
  mgsum[(b * NSEG + s) * DIM + t] = 0.f;
  for (int n = t; n < NPTS; n += 256) labS[n] = labels[b * NPTS + n];
  __syncthreads();
  float accf = 0.f;
  int cnt = 0;
  for (int n = 0; n < NPTS; n += 4) {
    const int4 l4 = *(const int4*)&labS[n];
    if (l4.x == s) { cnt++; accf += features[(b * NPTS + n + 0) * DIM + t]; }
    if (l4.y == s) { cnt++; accf += features[(b * NPTS + n + 1) * DIM + t]; }
    if (l4.z == s) { cnt++; accf += features[(b * NPTS + n + 2) * DIM + t]; }
    if (l4.w == s) { cnt++; accf += features[(b * NPTS + n + 3) * DIM + t]; }
  }
  const float denom = fmaxf((float)cnt, 1.f);
  mfS[t] = accf / denom;
  __syncthreads();
  float hval = 0.f;
  if (t < HID) {
    float o = ag_b1[t];
    for (int k = 0; k < DIM; k += 4) {
      const f32x4 x = *(const f32x4*)&mfS[k];
      const f32x4 w = *(const f32x4*)&ag_w1[t * DIM + k];
      o += x[0] * w[0] + x[1] * w[1] + x[2] * w[2] + x[3] * w[3];
    }
    hval = o;
  }
  float sv = (t < HID) ? hval : 0.f;
  float qv = (t < HID) ? hval * hval : 0.f;
  #pragma unroll
  for (int off = 1; off < 64; off <<= 1) { sv += __shfl_xor(sv, off); qv += __shfl_xor(qv, off); }
  if (lane == 0 && wid < 2) { red[wid * 2] = sv; red[wid * 2 + 1] = qv; }
  __syncthreads();
  if (t < HID) {
    const float s1 = red[0] + red[2], q1 = red[1] + red[3];
    const float mean = s1 * (1.f / 128.f);
    const float var = fmaxf(q1 * (1.f / 128.f) - mean * mean, 0.f);
    const float rs = rsqrtf(var + LN_EPS);
    h1S[t] = fmaxf((hval - mean) * rs * ag_g1[t] + ag_be1[t], 0.f);
  }
  __syncthreads();
  float o = ag_b2[t];
  for (int k = 0; k < HID; k += 4) {
    const f32x4 x = *(const f32x4*)&h1S[k];
    const f32x4 w = *(const f32x4*)&ag_w2[t * HID + k];
    o += x[0] * w[0] + x[1] * w[1] + x[2] * w[2] + x[3] * w[3];
  }
  float sv2 = o, qv2 = o * o;
  #pragma unroll
  for (int off = 1; off < 64; off <<= 1) { sv2 += __shfl_xor(sv2, off); qv2 += __shfl_xor(qv2, off); }
  if (lane == 0) { red[wid * 2] = sv2; red[wid * 2 + 1] = qv2; }
  __syncthreads();
  const float sa = red[0] + red[2] + red[4] + red[6];
  const float qa = red[1] + red[3] + red[5] + red[7];
  const float mean = sa * (1.f / 256.f);
  const float var = fmaxf(qa * (1.f / 256.f) - mean * mean, 0.f);
  const float rs = rsqrtf(var + LN_EPS);
  comb[(b * NSEG + s) * DIM + t] = (o - mean) * rs * ag_g2[t] + ag_be2[t];
  if (t == 0) cntf[b * NSEG + s] = (float)cnt;
}

// ---------------- K1: v6 core + mgsum atomics + K->Kt (transposed) and V epilogue --------
__global__ __launch_bounds__(256, 4) void k1_geo(
    fpc coords, const int* __restrict__ labels,
    fpc g1, fpc be1, fpc w1, fpc b1,
    fpc w2, fpc b2, fpc g2, fpc be2,
    fpc wkT, fpc bk, fpc wvT, fpc bv,
    const unsigned short* __restrict__ gmw, fpc uw, fpc tvw, fpc scw, fpc qfw,
    float* __restrict__ Kt, float* __restrict__ Vout, float* __restrict__ mgsum)
{
  const int t = threadIdx.x;
  const int lane = t & 63;
  const int wid = t >> 6;
  const int bi = blockIdx.x;           // b*512 + i
  const int b = bi >> 9;

  __shared__ __align__(16) float xs[NPTS][8];
  __shared__ __align__(16) float st[NPTS][2];
  __shared__ __align__(16) float qf[128];
  __shared__ __align__(16) unsigned short h1s[32][136];
  __shared__ __align__(16) float red2[32][12];
  __shared__ __align__(16) float haS[128];
  __shared__ __align__(16) float gS[256];
  __shared__ float srsS, srmS;

  if (t < 128) qf[t] = qfw[t];

  float w1r[2][7], b1r[2], g1r[2], be1r[2];
  #pragma unroll
  for (int r = 0; r < 2; ++r) {
    const int hh = lane * 2 + r;
    w1r[r][0] = w1[hh * 9 + 0]; w1r[r][1] = w1[hh * 9 + 1];
    w1r[r][2] = w1[hh * 9 + 2]; w1r[r][3] = w1[hh * 9 + 3];
    w1r[r][4] = w1[hh * 9 + 6]; w1r[r][5] = w1[hh * 9 + 7];
    w1r[r][6] = w1[hh * 9 + 8];
    b1r[r] = b1[hh]; g1r[r] = g1[hh]; be1r[r] = be1[hh];
  }
  const int n16 = lane & 15;
  const int q16 = lane >> 4;
  const int colc0 = wid * 32 + n16;
  s16x8 gfrag[2][4];
  float u_c[2], tv_c[2];
  #pragma unroll
  for (int dt = 0; dt < 2; ++dt) {
    const int c = colc0 + dt * 16;
    u_c[dt] = uw[c];
    tv_c[dt] = 2.f * tvw[c];
    #pragma unroll
    for (int kt = 0; kt < 4; ++kt)
      gfrag[dt][kt] = *(const s16x8*)&gmw[c * HID + kt * 32 + q16 * 8];
  }
  const float sb = scw[0], sb2 = scw[1];
  const float cix = coords[bi * 3 + 0];
  const float ciy = coords[bi * 3 + 1];
  const float ciz = coords[bi * 3 + 2];
  __syncthreads();

  #pragma unroll
  for (int jj = 0; jj < 2; ++jj) {
    const int j = t + jj * 256;
    const float cjx = coords[(b * NPTS + j) * 3 + 0];
    const float cjy = coords[(b * NPTS + j) * 3 + 1];
    const float cjz = coords[(b * NPTS + j) * 3 + 2];
    const float rx = cix - cjx, ry = ciy - cjy, rz = ciz - cjz;
    const float dist = sqrtf(rx * rx + ry * ry + rz * rz);
    const float inv = 1.f / fmaxf(dist, 1e-12f);
    const float r0 = rx * inv, r1 = ry * inv, r2 = rz * inv;
    const float x0 = dist, x1 = r0, x2 = r1, x3 = r2;
    const float x6 = r1 * r2, x7 = r0 * r1, x8 = r0 * r2;
    float S1 = qf[126] + qf[108] * x0 + qf[109] * x1 + qf[110] * x2 + qf[111] * x3
             + qf[114] * x6 + qf[115] * x7 + qf[116] * x8;
    float tx = qf[117] * x0 + qf[118] * x1 + qf[119] * x2 + qf[120] * x3
             + qf[123] * x6 + qf[124] * x7 + qf[125] * x8;
    const float xv[9] = {x0, x1, x2, x3, 0.f, 0.f, x6, x7, x8};
    float quad = 0.f;
    #pragma unroll
    for (int a = 0; a < 9; ++a) {
      if (a == 4 || a == 5) continue;
      const f32x4 q0 = *(const f32x4*)&qf[a * 12];
      const f32x4 q1 = *(const f32x4*)&qf[a * 12 + 4];
      const f32x4 q2 = *(const f32x4*)&qf[a * 12 + 8];
      const float ya = q0[0] * x0 + q0[1] * x1 + q0[2] * x2 + q0[3] * x3
                     + q1[2] * x6 + q1[3] * x7 + q2[0] * x8;
      quad += ya * xv[a];
    }
    const float S2 = quad + 2.f * tx + qf[127];
    const float mean = S1 * (1.f / 128.f);
    const float var = fmaxf(S2 * (1.f / 128.f) - mean * mean, 0.f);
    st[j][0] = mean;
    st[j][1] = rsqrtf(var + LN_EPS);
    f32x4 X0; X0[0] = x0; X0[1] = x1; X0[2] = x2; X0[3] = x3;
    f32x4 X1; X1[0] = x6; X1[1] = x7; X1[2] = x8; X1[3] = 0.f;
    *(f32x4*)&xs[j][0] = X0;
    *(f32x4*)&xs[j][4] = X1;
  }
  __syncthreads();

  float haL[2] = {0.f, 0.f};
  float srs = 0.f, srm = 0.f;
  const bool own = (wid == 0) && (n16 == 0);

  for (int jb = 0; jb < NPTS; jb += 32) {
    #pragma unroll
    for (int sr = 0; sr < 8; ++sr) {
      const int m = sr * 4 + wid;
      const int j = jb + m;
      const f32x4 X0 = *(const f32x4*)&xs[j][0];
      const f32x4 X1 = *(const f32x4*)&xs[j][4];
      const float2 ms = *(const float2*)&st[j][0];
      unsigned int pk = 0;
      #pragma unroll
      for (int r = 0; r < 2; ++r) {
        const float a = b1r[r]
          + X0[0] * w1r[r][0] + X0[1] * w1r[r][1] + X0[2] * w1r[r][2] + X0[3] * w1r[r][3]
          + X1[0] * w1r[r][4] + X1[1] * w1r[r][5] + X1[2] * w1r[r][6];
        const float e = (a - ms.x) * ms.y * g1r[r] + be1r[r];
        pk |= ((unsigned int)f2bf(fmaxf(e, 0.f))) << (16 * r);
      }
      *(unsigned int*)&h1s[m][lane * 2] = pk;
    }
    __syncthreads();
    f32x4 acc2[2][2];
    #pragma unroll
    for (int mt = 0; mt < 2; ++mt)
      #pragma unroll
      for (int dt = 0; dt < 2; ++dt) {
        f32x4 z; z[0] = tv_c[dt]; z[1] = tv_c[dt]; z[2] = tv_c[dt]; z[3] = tv_c[dt];
        acc2[mt][dt] = z;
      }
    #pragma unroll
    for (int mt = 0; mt < 2; ++mt)
      #pragma unroll
      for (int kt = 0; kt < 4; ++kt) {
        const s16x8 af = *(const s16x8*)&h1s[mt * 16 + n16][kt * 32 + q16 * 8];
        #pragma unroll
        for (int dt = 0; dt < 2; ++dt)
          acc2[mt][dt] = __builtin_amdgcn_mfma_f32_16x16x32_bf16(af, gfrag[dt][kt], acc2[mt][dt], 0, 0, 0);
      }
    float h1v[2][2][4];
    #pragma unroll
    for (int mt = 0; mt < 2; ++mt)
      #pragma unroll
      for (int dt = 0; dt < 2; ++dt)
        #pragma unroll
        for (int r = 0; r < 4; ++r) {
          const unsigned short hv = h1s[mt * 16 + q16 * 4 + r][colc0 + dt * 16];
          h1v[mt][dt][r] = __builtin_bit_cast(float, ((unsigned int)hv) << 16);
        }
    #pragma unroll
    for (int mt = 0; mt < 2; ++mt) {
      float sR[4], qR[4];
      #pragma unroll
      for (int r = 0; r < 4; ++r) {
        sR[r] = u_c[0] * h1v[mt][0][r] + u_c[1] * h1v[mt][1][r];
        qR[r] = acc2[mt][0][r] * h1v[mt][0][r] + acc2[mt][1][r] * h1v[mt][1][r];
      }
      #pragma unroll
      for (int off = 1; off < 16; off <<= 1)
        #pragma unroll
        for (int r = 0; r < 4; ++r) {
          sR[r] += __shfl_xor(sR[r], off);
          qR[r] += __shfl_xor(qR[r], off);
        }
      if (n16 == 0)
        #pragma unroll
        for (int r = 0; r < 4; ++r) {
          red2[mt * 16 + q16 * 4 + r][wid * 2 + 0] = sR[r];
          red2[mt * 16 + q16 * 4 + r][wid * 2 + 1] = qR[r];
        }
    }
    __syncthreads();
    #pragma unroll
    for (int mt = 0; mt < 2; ++mt)
      #pragma unroll
      for (int r = 0; r < 4; ++r) {
        const int row = mt * 16 + q16 * 4 + r;
        const f32x4 p0 = *(const f32x4*)&red2[row][0];
        const f32x4 p1 = *(const f32x4*)&red2[row][4];
        const float s = p0[0] + p0[2] + p1[0] + p1[2];
        const float q = p0[1] + p0[3] + p1[1] + p1[3];
        const float mean = (s + sb) * (1.f / 256.f);
        const float var = fmaxf((q + sb2) * (1.f / 256.f) - mean * mean, 0.f);
        const float rs = rsqrtf(var + LN_EPS);
        haL[0] += rs * h1v[mt][0][r];
        haL[1] += rs * h1v[mt][1][r];
        if (own) { srs += rs; srm += rs * mean; }
      }
  }

  haL[0] += __shfl_xor(haL[0], 16); haL[0] += __shfl_xor(haL[0], 32);
  haL[1] += __shfl_xor(haL[1], 16); haL[1] += __shfl_xor(haL[1], 32);
  float sa = srs, sm = srm;
  sa += __shfl_xor(sa, 16); sa += __shfl_xor(sa, 32);
  sm += __shfl_xor(sm, 16); sm += __shfl_xor(sm, 32);
  if (t == 0) { srsS = sa; srmS = sm; }
  if (lane < 16) { haS[colc0] = haL[0]; haS[colc0 + 16] = haL[1]; }
  __syncthreads();
  const float srsT = srsS, srmT = srmS;
  float dot = 0.f;
  for (int k = 0; k < HID; k += 4) {
    const f32x4 w = *(const f32x4*)&w2[t * HID + k];
    const f32x4 h = *(const f32x4*)&haS[k];
    dot += w[0] * h[0] + w[1] * h[1] + w[2] * h[2] + w[3] * h[3];
  }
  const float gv = (dot + b2[t] * srsT - srmT) * (1.f / 512.f) * g2[t] + be2[t];
  gS[t] = gv;
  const int l = labels[bi];
  atomicAdd(&mgsum[(b * NSEG + l) * DIM + t], gv);
  __syncthreads();
  // ---- K/V rows via transposed weights (coalesced); K stored TRANSPOSED for k5 scores
  float kacc = bk[t], vacc = bv[t];
  for (int k = 0; k < DIM; k += 4) {
    const f32x4 g4 = *(const f32x4*)&gS[k];
    kacc += g4[0] * wkT[(k + 0) * DIM + t] + g4[1] * wkT[(k + 1) * DIM + t]
          + g4[2] * wkT[(k + 2) * DIM + t] + g4[3] * wkT[(k + 3) * DIM + t];
    vacc += g4[0] * wvT[(k + 0) * DIM + t] + g4[1] * wvT[(k + 1) * DIM + t]
          + g4[2] * wvT[(k + 2) * DIM + t] + g4[3] * wvT[(k + 3) * DIM + t];
  }
  // Kt[b][h=t>>5][d=t&31][k=bi&511] — scattered store (fire-and-forget), coalesced READ in k5
  Kt[((b * 8 + (t >> 5)) * 32 + (t & 31)) * KTS + (bi & 511)] = kacc;
  Vout[bi * DIM + t] = vacc;
}

// ---------------- K5 v3: 1 row/block, all loads lane-consecutive --------------------------
// v10 lesson: score phase read K per-lane-row (1KB lane stride = 64 lines/instr) — same
// pathology as v9's wk. v11: scores from Kt (k-major, f32x4 over k), Q/wo proj from
// wqT/woT (uniform scalar x coalesced vector), PV keeps baseline 16-lane-broadcast form.
// Grid 1024 = 4 blocks/CU = 16 waves/CU.
__global__ __launch_bounds__(256, 4) void k5_fused(
    fpc features, const int* __restrict__ labels,
    fpc comb, fpc cntf, fpc mgsum,
    fpc Kt, fpc V, fpc wqT, fpc bq, fpc woT, fpc bo,
    float* __restrict__ out)
{
  const int row = blockIdx.x;          // global row 0..1023
  const int b = row >> 9;
  const int t = threadIdx.x;
  const int w = t >> 6;                // wave 0..3 -> heads 2w, 2w+1; cols w*64..w*64+63
  const int l = t & 63;
  __shared__ __align__(16) float E[256];
  __shared__ __align__(16) float Qs[256];
  __shared__ __align__(16) float Px[4][512];
  __shared__ __align__(16) float OcS[256];

  // ---- enh row (all 256 threads, scalar col t)
  {
    const int lab = labels[row];
    const float cn = cntf[b * NSEG + lab];
    const float f = features[row * DIM + t];
    float v = f;
    if (cn >= 2.f) {
      const float ag = comb[(b * NSEG + lab) * DIM + t];
      const float mg = mgsum[(b * NSEG + lab) * DIM + t];
      v = 0.7f * f + 0.3f * (ag + mg / cn);
    }
    E[t] = v;
  }
  __syncthreads();
  // ---- Q proj: lane group (l&15) covers 4 cols, quarter (l>>4) splits k; coalesced wqT
  {
    const int c4 = w * 64 + (l & 15) * 4;
    const int k0 = (l >> 4) * 64;
    f32x4 q4 = {0.f, 0.f, 0.f, 0.f};
    for (int k = k0; k < k0 + 64; ++k) {
      const float e = E[k];
      const f32x4 wv4 = *(const f32x4*)&wqT[k * DIM + c4];
      #pragma unroll
      for (int i = 0; i < 4; ++i) q4[i] += e * wv4[i];
    }
    #pragma unroll
    for (int i = 0; i < 4; ++i) { q4[i] += __shfl_xor(q4[i], 16); q4[i] += __shfl_xor(q4[i], 32); }
    if (l < 16) {
      const f32x4 bq4 = *(const f32x4*)&bq[c4];
      f32x4 o;
      #pragma unroll
      for (int i = 0; i < 4; ++i) o[i] = q4[i] + bq4[i];
      *(f32x4*)&Qs[c4] = o;
    }
  }
  // ---- per-head: scores (Kt, coalesced f32x4 over k) -> wave softmax -> PV -> OcS
  for (int hi = 0; hi < 2; ++hi) {
    const int h = w * 2 + hi;
    f32x4 s4[2] = {{0.f, 0.f, 0.f, 0.f}, {0.f, 0.f, 0.f, 0.f}};
    const long kbase = (long)((b * 8 + h) * 32) * KTS;
    for (int d = 0; d < 32; ++d) {
      const float qd = Qs[h * 32 + d];
      const fpc kr = &Kt[kbase + (long)d * KTS];
      const f32x4 k0v = *(const f32x4*)&kr[l * 4];
      const f32x4 k1v = *(const f32x4*)&kr[256 + l * 4];
      #pragma unroll
      for (int i = 0; i < 4; ++i) { s4[0][i] += qd * k0v[i]; s4[1][i] += qd * k1v[i]; }
    }
    #pragma unroll
    for (int i = 0; i < 4; ++i) {
      s4[0][i] *= 0.1767766952966369f;
      s4[1][i] *= 0.1767766952966369f;
    }
    float mx = s4[0][0];
    #pragma unroll
    for (int i = 1; i < 4; ++i) mx = fmaxf(mx, s4[0][i]);
    #pragma unroll
    for (int i = 0; i < 4; ++i) mx = fmaxf(mx, s4[1][i]);
    #pragma unroll
    for (int off = 1; off < 64; off <<= 1) mx = fmaxf(mx, __shfl_xor(mx, off));
    f32x4 p0, p1;
    float sum = 0.f;
    #pragma unroll
    for (int i = 0; i < 4; ++i) { p0[i] = __expf(s4[0][i] - mx); sum += p0[i]; }
    #pragma unroll
    for (int i = 0; i < 4; ++i) { p1[i] = __expf(s4[1][i] - mx); sum += p1[i]; }
    #pragma unroll
    for (int off = 1; off < 64; off <<= 1) sum += __shfl_xor(sum, off);
    const float ri = 1.f / sum;
    #pragma unroll
    for (int i = 0; i < 4; ++i) { p0[i] *= ri; p1[i] *= ri; }
    *(f32x4*)&Px[w][l * 4] = p0;
    *(f32x4*)&Px[w][256 + l * 4] = p1;
    // PV baseline-style: group (l>>4) = k-quarter, (l&15)*2 = dim pair; V row broadcast
    const int j2 = (l & 15) * 2;
    const int k0 = (l >> 4) * 128;
    float o0 = 0.f, o1 = 0.f;
    for (int k = k0; k < k0 + 128; ++k) {
      const float pv = Px[w][k];
      const float2 vv = *(const float2*)&V[(b * NPTS + k) * DIM + h * 32 + j2];
      o0 += pv * vv.x; o1 += pv * vv.y;
    }
    o0 += __shfl_xor(o0, 16); o1 += __shfl_xor(o1, 16);
    o0 += __shfl_xor(o0, 32); o1 += __shfl_xor(o1, 32);
    if (l < 16) { OcS[h * 32 + j2] = o0; OcS[h * 32 + j2 + 1] = o1; }
  }
  __syncthreads();
  // ---- wo proj + epilogue: same split as Q proj; coalesced woT
  {
    const int c4 = w * 64 + (l & 15) * 4;
    const int j0 = (l >> 4) * 64;
    f32x4 d4 = {0.f, 0.f, 0.f, 0.f};
    for (int j = j0; j < j0 + 64; ++j) {
      const float oc = OcS[j];
      const f32x4 wv4 = *(const f32x4*)&woT[j * DIM + c4];
      #pragma unroll
      for (int i = 0; i < 4; ++i) d4[i] += oc * wv4[i];
    }
    #pragma unroll
    for (int i = 0; i < 4; ++i) { d4[i] += __shfl_xor(d4[i], 16); d4[i] += __shfl_xor(d4[i], 32); }
    if (l < 16) {
      const f32x4 bo4 = *(const f32x4*)&bo[c4];
      const f32x4 e4 = *(const f32x4*)&E[c4];
      f32x4 o;
      #pragma unroll
      for (int i = 0; i < 4; ++i) o[i] = e4[i] + 0.5f * (d4[i] + bo4[i]);
      *(f32x4*)&out[row * DIM + c4] = o;
    }
  }
}

extern "C" void kernel_launch(void* const* d_in, const int* in_sizes, int n_in,
                              void* d_out, int out_size, void* d_ws, size_t ws_size,
                              hipStream_t stream)
{
  fpc coords  = (fpc)d_in[0];
  fpc features= (fpc)d_in[1];
  const int* labels = (const int*)d_in[2];
  fpc ge_w1 = (fpc)d_in[3],  ge_b1 = (fpc)d_in[4],  ge_g1 = (fpc)d_in[5],  ge_be1 = (fpc)d_in[6];
  fpc ge_w2 = (fpc)d_in[7],  ge_b2 = (fpc)d_in[8],  ge_g2 = (fpc)d_in[9],  ge_be2 = (fpc)d_in[10];
  fpc ag_w1 = (fpc)d_in[11], ag_b1 = (fpc)d_in[12], ag_g1 = (fpc)d_in[13], ag_be1 = (fpc)d_in[14];
  fpc ag_w2 = (fpc)d_in[15], ag_b2 = (fpc)d_in[16], ag_g2 = (fpc)d_in[17], ag_be2 = (fpc)d_in[18];
  fpc wq = (fpc)d_in[19], bq = (fpc)d_in[20];
  fpc wk = (fpc)d_in[21], bk = (fpc)d_in[22];
  fpc wv = (fpc)d_in[23], bv = (fpc)d_in[24];
  fpc wo = (fpc)d_in[25], bo = (fpc)d_in[26];

  float* ws = (float*)d_ws;
  float* comb    = ws;                    // 32768
  float* cntf    = comb + 32768;          // 128
  float* Vb      = cntf + 128;            // 262144
  float* Ktb     = Vb + 262144;           // 266240 (2*8*32*520)
  float* mgsum   = Ktb + 266240;          // 32768
  float* gmwF    = mgsum + 32768;         // 8192
  float* uw      = gmwF + 8192;           // 128
  float* tvw     = uw + 128;              // 128
  float* scw     = tvw + 128;             // 8
  float* qfw     = scw + 8;               // 128
  float* wkT     = qfw + 128;             // 65536
  float* wvT     = wkT + 65536;           // 65536
  float* wqT     = wvT + 65536;           // 65536
  float* woT     = wqT + 65536;           // 65536

  k02_prep_agg<<<290, 256, 0, stream>>>(ge_w1, ge_b1, ge_w2, ge_b2,
                                        features, labels, wk, wv, wq, wo,
                                        ag_w1, ag_b1, ag_g1, ag_be1,
                                        ag_w2, ag_b2, ag_g2, ag_be2,
                                        (unsigned short*)gmwF, uw, tvw, scw, qfw,
                                        wkT, wvT, wqT, woT, comb, cntf, mgsum);
  k1_geo<<<1024, 256, 0, stream>>>(coords, labels, ge_g1, ge_be1, ge_w1, ge_b1,
                                   ge_w2, ge_b2, ge_g2, ge_be2,
                                   wkT, bk, wvT, bv,
                                   (const unsigned short*)gmwF, uw, tvw, scw, qfw,
                                   Ktb, Vb, mgsum);
  k5_fused<<<1024, 256, 0, stream>>>(features, labels, comb, cntf, mgsum,
                                     Ktb, Vb, wqT, bq, woT, bo, (float*)d_out);
}

// Round 9
// 321.714 us; speedup vs baseline: 1.6432x; 1.0068x over previous
//
#include <hip/hip_runtime.h>

#define NPTS 512
#define DIM  256
#define HID  128
#define NSEG 64
#define LN_EPS 1e-5f
#define KTS 520   // Kt row stride (floats): breaks 2KB power-of-2 channel aliasing

typedef short s16x4 __attribute__((ext_vector_type(4)));
typedef short s16x8 __attribute__((ext_vector_type(8)));
typedef float f32x4 __attribute__((ext_vector_type(4)));
typedef const float* fpc;

__device__ __forceinline__ unsigned short f2bf(float f) {
  unsigned int u = __builtin_bit_cast(unsigned int, f);
  u += 0x7FFFu + ((u >> 16) & 1u);
  return (unsigned short)(u >> 16);
}

// ---------------- K02: prep + transposes (wk,wv,wq,wo) + aggregator + mgsum zero ---------
__global__ void k02_prep_agg(
    fpc ge_w1, fpc ge_b1, fpc ge_w2, fpc ge_b2,
    fpc features, const int* __restrict__ labels,
    fpc wk, fpc wv, fpc wq, fpc wo,
    fpc ag_w1, fpc ag_b1, fpc ag_g1, fpc ag_be1,
    fpc ag_w2, fpc ag_b2, fpc ag_g2, fpc ag_be2,
    unsigned short* __restrict__ gmw, float* __restrict__ uw,
    float* __restrict__ tvw, float* __restrict__ scw, float* __restrict__ qfw,
    float* __restrict__ wkT, float* __restrict__ wvT,
    float* __restrict__ wqT, float* __restrict__ woT,
    float* __restrict__ comb, float* __restrict__ cntf, float* __restrict__ mgsum)
{
  const int blk = blockIdx.x;
  const int t = threadIdx.x;
  if (blk < 130) {                       // ---- prep (t<128 active)
    if (t < 128) {
      if (blk < 128) {
        const int c = blk;
        float acc = 0.f;
        for (int d = 0; d < DIM; ++d) acc += ge_w2[d * HID + c] * ge_w2[d * HID + t];
        gmw[c * HID + t] = f2bf(acc);
      } else if (blk == 128) {
        float uu = 0.f, tv = 0.f;
        for (int d = 0; d < DIM; ++d) { const float w = ge_w2[d * HID + t]; uu += w; tv += ge_b2[d] * w; }
        uw[t] = uu; tvw[t] = tv;
        if (t == 0) {
          float s = 0.f, s2 = 0.f;
          for (int d = 0; d < DIM; ++d) { const float bb = ge_b2[d]; s += bb; s2 += bb * bb; }
          scw[0] = s; scw[1] = s2;
        }
      } else {
        if (t < 101) {
          float acc = 0.f;
          if (t < 81) {
            const int a = t / 9, c = t % 9;
            for (int h = 0; h < HID; ++h) acc += ge_w1[h * 9 + a] * ge_w1[h * 9 + c];
            qfw[a * 12 + c] = acc;
          } else if (t < 90) {
            const int a = t - 81;
            for (int h = 0; h < HID; ++h) acc += ge_w1[h * 9 + a];
            qfw[108 + a] = acc;
          } else if (t < 99) {
            const int a = t - 90;
            for (int h = 0; h < HID; ++h) acc += ge_b1[h] * ge_w1[h * 9 + a];
            qfw[117 + a] = acc;
          } else if (t == 99) {
            float acc2 = 0.f;
            for (int h = 0; h < HID; ++h) acc2 += ge_b1[h];
            qfw[126] = acc2;
          } else {
            float acc2 = 0.f;
            for (int h = 0; h < HID; ++h) acc2 += ge_b1[h] * ge_b1[h];
            qfw[127] = acc2;
          }
        }
      }
    }
    return;
  }
  if (blk < 162) {                       // ---- transpose 4 matrices x 8 col-strips
    __shared__ __align__(16) float T[32][256];
    const int tr = blk - 130;
    const int m = tr >> 3;
    fpc src = (m == 0) ? wk : (m == 1) ? wv : (m == 2) ? wq : wo;
    float* dst = (m == 0) ? wkT : (m == 1) ? wvT : (m == 2) ? wqT : woT;
    const int c0 = (tr & 7) * 32;
    for (int i = 0; i < 32; ++i) T[i][t] = src[(c0 + i) * DIM + t];   // coalesced reads
    __syncthreads();
    #pragma unroll
    for (int j4 = 0; j4 < 32; j4 += 4) {
      f32x4 v;
      v[0] = T[j4 + 0][t]; v[1] = T[j4 + 1][t];
      v[2] = T[j4 + 2][t]; v[3] = T[j4 + 3][t];
      *(f32x4*)&dst[t * DIM + c0 + j4] = v;   // dst[k=t][c] = src[c][k]
    }
    return;
  }
  // ---- aggregator (mg-free) + mgsum zero
  const int item = blk - 162;
  const int lane = t & 63;
  const int wid = t >> 6;
  const int b = item >> 6;
  const int s = item & 63;
  __shared__ __align__(16) int labS[NPTS];
  __shared__ __align__(16) float mfS[DIM];
  __shared__ __align__(16) float h1S[HID];
  __shared__ __align__(16) float red[8];
  mgsum[(b * NSEG + s) * DIM + t] = 0.f;
  for (int n = t; n < NPTS; n += 256) labS[n] = labels[b * NPTS + n];
  __syncthreads();
  float accf = 0.f;
  int cnt = 0;
  for (int n = 0; n < NPTS; n += 4) {
    const int4 l4 = *(const int4*)&labS[n];
    if (l4.x == s) { cnt++; accf += features[(b * NPTS + n + 0) * DIM + t]; }
    if (l4.y == s) { cnt++; accf += features[(b * NPTS + n + 1) * DIM + t]; }
    if (l4.z == s) { cnt++; accf += features[(b * NPTS + n + 2) * DIM + t]; }
    if (l4.w == s) { cnt++; accf += features[(b * NPTS + n + 3) * DIM + t]; }
  }
  const float denom = fmaxf((float)cnt, 1.f);
  mfS[t] = accf / denom;
  __syncthreads();
  float hval = 0.f;
  if (t < HID) {
    float o = ag_b1[t];
    for (int k = 0; k < DIM; k += 4) {
      const f32x4 x = *(const f32x4*)&mfS[k];
      const f32x4 w = *(const f32x4*)&ag_w1[t * DIM + k];
      o += x[0] * w[0] + x[1] * w[1] + x[2] * w[2] + x[3] * w[3];
    }
    hval = o;
  }
  float sv = (t < HID) ? hval : 0.f;
  float qv = (t < HID) ? hval * hval : 0.f;
  #pragma unroll
  for (int off = 1; off < 64; off <<= 1) { sv += __shfl_xor(sv, off); qv += __shfl_xor(qv, off); }
  if (lane == 0 && wid < 2) { red[wid * 2] = sv; red[wid * 2 + 1] = qv; }
  __syncthreads();
  if (t < HID) {
    const float s1 = red[0] + red[2], q1 = red[1] + red[3];
    const float mean = s1 * (1.f / 128.f);
    const float var = fmaxf(q1 * (1.f / 128.f) - mean * mean, 0.f);
    const float rs = rsqrtf(var + LN_EPS);
    h1S[t] = fmaxf((hval - mean) * rs * ag_g1[t] + ag_be1[t], 0.f);
  }
  __syncthreads();
  float o = ag_b2[t];
  for (int k = 0; k < HID; k += 4) {
    const f32x4 x = *(const f32x4*)&h1S[k];
    const f32x4 w = *(const f32x4*)&ag_w2[t * HID + k];
    o += x[0] * w[0] + x[1] * w[1] + x[2] * w[2] + x[3] * w[3];
  }
  float sv2 = o, qv2 = o * o;
  #pragma unroll
  for (int off = 1; off < 64; off <<= 1) { sv2 += __shfl_xor(sv2, off); qv2 += __shfl_xor(qv2, off); }
  if (lane == 0) { red[wid * 2] = sv2; red[wid * 2 + 1] = qv2; }
  __syncthreads();
  const float sa = red[0] + red[2] + red[4] + red[6];
  const float qa = red[1] + red[3] + red[5] + red[7];
  const float mean = sa * (1.f / 256.f);
  const float var = fmaxf(qa * (1.f / 256.f) - mean * mean, 0.f);
  const float rs = rsqrtf(var + LN_EPS);
  comb[(b * NSEG + s) * DIM + t] = (o - mean) * rs * ag_g2[t] + ag_be2[t];
  if (t == 0) cntf[b * NSEG + s] = (float)cnt;
}

// ---------------- K1 v12: 512-thread / 8-wave blocks ------------------------------------
// v11 k1 = 140us at Occ 34%, VALUBusy 44%, VGPR 64 — stall-bound at 16 waves/CU, and
// grid 1024 = exactly 4 blocks/CU so LDS shrink can't raise residency. v12: 512-thr
// blocks, wave w=(mtw=w>>2, cg=w&3) owns ONE m-tile x 2 col-tiles (per-wave state halves:
// acc2[2], h1v[2][4]). 4 blocks x 8 waves = 32 waves/CU (2x) iff VGPR stays <=64 (it was
// 64 with MORE live state). launch_bounds(512,4): cap 128, no forcing (v4 lesson).
// K/V epilogue split: t<256 -> K, t>=256 -> V (halves epilogue latency too).
__global__ __launch_bounds__(512, 4) void k1_geo(
    fpc coords, const int* __restrict__ labels,
    fpc g1, fpc be1, fpc w1, fpc b1,
    fpc w2, fpc b2, fpc g2, fpc be2,
    fpc wkT, fpc bk, fpc wvT, fpc bv,
    const unsigned short* __restrict__ gmw, fpc uw, fpc tvw, fpc scw, fpc qfw,
    float* __restrict__ Kt, float* __restrict__ Vout, float* __restrict__ mgsum)
{
  const int t = threadIdx.x;           // 0..511
  const int lane = t & 63;
  const int w = t >> 6;                // wave 0..7
  const int mtw = w >> 2;              // m-tile 0..1
  const int cg = w & 3;                // col group 0..3
  const int bi = blockIdx.x;           // b*512 + i
  const int b = bi >> 9;

  __shared__ __align__(16) float xs[NPTS][8];            // 16K
  __shared__ __align__(16) float st[NPTS][2];            // 4K
  __shared__ __align__(16) float qf[128];                // .5K
  __shared__ __align__(16) unsigned short h1s[32][136];  // 8.5K
  __shared__ __align__(16) float red2[32][12];           // 1.5K
  __shared__ __align__(16) float haS[2][128];            // 1K
  __shared__ __align__(16) float gS[256];                // 1K
  __shared__ float srsP[2], srmP[2];

  if (t < 128) qf[t] = qfw[t];

  // phase-A weights: 2 channels per lane (same per-wave copy as v6)
  float w1r[2][7], b1r[2], g1r[2], be1r[2];
  #pragma unroll
  for (int r = 0; r < 2; ++r) {
    const int hh = lane * 2 + r;
    w1r[r][0] = w1[hh * 9 + 0]; w1r[r][1] = w1[hh * 9 + 1];
    w1r[r][2] = w1[hh * 9 + 2]; w1r[r][3] = w1[hh * 9 + 3];
    w1r[r][4] = w1[hh * 9 + 6]; w1r[r][5] = w1[hh * 9 + 7];
    w1r[r][6] = w1[hh * 9 + 8];
    b1r[r] = b1[hh]; g1r[r] = g1[hh]; be1r[r] = be1[hh];
  }
  const int n16 = lane & 15;
  const int q16 = lane >> 4;
  const int colc0 = cg * 32 + n16;
  s16x8 gfrag[2][4];
  float u_c[2], tv_c[2];
  #pragma unroll
  for (int dt = 0; dt < 2; ++dt) {
    const int c = colc0 + dt * 16;
    u_c[dt] = uw[c];
    tv_c[dt] = 2.f * tvw[c];
    #pragma unroll
    for (int kt = 0; kt < 4; ++kt)
      gfrag[dt][kt] = *(const s16x8*)&gmw[c * HID + kt * 32 + q16 * 8];
  }
  const float sb = scw[0], sb2 = scw[1];
  const float cix = coords[bi * 3 + 0];
  const float ciy = coords[bi * 3 + 1];
  const float ciz = coords[bi * 3 + 2];
  __syncthreads();

  // ---- startup B: x + LN1 stats, 1 j per thread
  {
    const int j = t;
    const float cjx = coords[(b * NPTS + j) * 3 + 0];
    const float cjy = coords[(b * NPTS + j) * 3 + 1];
    const float cjz = coords[(b * NPTS + j) * 3 + 2];
    const float rx = cix - cjx, ry = ciy - cjy, rz = ciz - cjz;
    const float dist = sqrtf(rx * rx + ry * ry + rz * rz);
    const float inv = 1.f / fmaxf(dist, 1e-12f);
    const float r0 = rx * inv, r1 = ry * inv, r2 = rz * inv;
    const float x0 = dist, x1 = r0, x2 = r1, x3 = r2;
    const float x6 = r1 * r2, x7 = r0 * r1, x8 = r0 * r2;
    float S1 = qf[126] + qf[108] * x0 + qf[109] * x1 + qf[110] * x2 + qf[111] * x3
             + qf[114] * x6 + qf[115] * x7 + qf[116] * x8;
    float tx = qf[117] * x0 + qf[118] * x1 + qf[119] * x2 + qf[120] * x3
             + qf[123] * x6 + qf[124] * x7 + qf[125] * x8;
    const float xv[9] = {x0, x1, x2, x3, 0.f, 0.f, x6, x7, x8};
    float quad = 0.f;
    #pragma unroll
    for (int a = 0; a < 9; ++a) {
      if (a == 4 || a == 5) continue;
      const f32x4 q0 = *(const f32x4*)&qf[a * 12];
      const f32x4 q1 = *(const f32x4*)&qf[a * 12 + 4];
      const f32x4 q2 = *(const f32x4*)&qf[a * 12 + 8];
      const float ya = q0[0] * x0 + q0[1] * x1 + q0[2] * x2 + q0[3] * x3
                     + q1[2] * x6 + q1[3] * x7 + q2[0] * x8;
      quad += ya * xv[a];
    }
    const float S2 = quad + 2.f * tx + qf[127];
    const float mean = S1 * (1.f / 128.f);
    const float var = fmaxf(S2 * (1.f / 128.f) - mean * mean, 0.f);
    st[j][0] = mean;
    st[j][1] = rsqrtf(var + LN_EPS);
    f32x4 X0; X0[0] = x0; X0[1] = x1; X0[2] = x2; X0[3] = x3;
    f32x4 X1; X1[0] = x6; X1[1] = x7; X1[2] = x8; X1[3] = 0.f;
    *(f32x4*)&xs[j][0] = X0;
    *(f32x4*)&xs[j][4] = X1;
  }
  __syncthreads();

  float haL[2] = {0.f, 0.f};
  float srs = 0.f, srm = 0.f;
  const bool own = (cg == 0) && (n16 == 0);   // each row counted once (per its mtw)

  for (int jb = 0; jb < NPTS; jb += 32) {
    // ---- phase A: 32 rows, m = sr*8 + w (4 passes x 8 waves)
    #pragma unroll
    for (int sr = 0; sr < 4; ++sr) {
      const int m = sr * 8 + w;
      const int j = jb + m;
      const f32x4 X0 = *(const f32x4*)&xs[j][0];
      const f32x4 X1 = *(const f32x4*)&xs[j][4];
      const float2 ms = *(const float2*)&st[j][0];
      unsigned int pk = 0;
      #pragma unroll
      for (int r = 0; r < 2; ++r) {
        const float a = b1r[r]
          + X0[0] * w1r[r][0] + X0[1] * w1r[r][1] + X0[2] * w1r[r][2] + X0[3] * w1r[r][3]
          + X1[0] * w1r[r][4] + X1[1] * w1r[r][5] + X1[2] * w1r[r][6];
        const float e = (a - ms.x) * ms.y * g1r[r] + be1r[r];
        pk |= ((unsigned int)f2bf(fmaxf(e, 0.f))) << (16 * r);
      }
      *(unsigned int*)&h1s[m][lane * 2] = pk;
    }
    __syncthreads();
    // ---- MFMA: this wave's m-tile only (8 MFMA)
    f32x4 acc2[2];
    #pragma unroll
    for (int dt = 0; dt < 2; ++dt) {
      f32x4 z; z[0] = tv_c[dt]; z[1] = tv_c[dt]; z[2] = tv_c[dt]; z[3] = tv_c[dt];
      acc2[dt] = z;
    }
    #pragma unroll
    for (int kt = 0; kt < 4; ++kt) {
      const s16x8 af = *(const s16x8*)&h1s[mtw * 16 + n16][kt * 32 + q16 * 8];
      #pragma unroll
      for (int dt = 0; dt < 2; ++dt)
        acc2[dt] = __builtin_amdgcn_mfma_f32_16x16x32_bf16(af, gfrag[dt][kt], acc2[dt], 0, 0, 0);
    }
    float h1v[2][4];
    #pragma unroll
    for (int dt = 0; dt < 2; ++dt)
      #pragma unroll
      for (int r = 0; r < 4; ++r) {
        const unsigned short hv = h1s[mtw * 16 + q16 * 4 + r][colc0 + dt * 16];
        h1v[dt][r] = __builtin_bit_cast(float, ((unsigned int)hv) << 16);
      }
    float sR[4], qR[4];
    #pragma unroll
    for (int r = 0; r < 4; ++r) {
      sR[r] = u_c[0] * h1v[0][r] + u_c[1] * h1v[1][r];
      qR[r] = acc2[0][r] * h1v[0][r] + acc2[1][r] * h1v[1][r];
    }
    #pragma unroll
    for (int off = 1; off < 16; off <<= 1)
      #pragma unroll
      for (int r = 0; r < 4; ++r) {
        sR[r] += __shfl_xor(sR[r], off);
        qR[r] += __shfl_xor(qR[r], off);
      }
    if (n16 == 0)
      #pragma unroll
      for (int r = 0; r < 4; ++r) {
        red2[mtw * 16 + q16 * 4 + r][cg * 2 + 0] = sR[r];
        red2[mtw * 16 + q16 * 4 + r][cg * 2 + 1] = qR[r];
      }
    __syncthreads();
    // ---- epilogue: this wave's mtw rows; accg += rs*h1 (linearized LN2)
    #pragma unroll
    for (int r = 0; r < 4; ++r) {
      const int row = mtw * 16 + q16 * 4 + r;
      const f32x4 p0 = *(const f32x4*)&red2[row][0];
      const f32x4 p1 = *(const f32x4*)&red2[row][4];
      const float s = p0[0] + p0[2] + p1[0] + p1[2];
      const float q = p0[1] + p0[3] + p1[1] + p1[3];
      const float mean = (s + sb) * (1.f / 256.f);
      const float var = fmaxf((q + sb2) * (1.f / 256.f) - mean * mean, 0.f);
      const float rs = rsqrtf(var + LN_EPS);
      haL[0] += rs * h1v[0][r];
      haL[1] += rs * h1v[1][r];
      if (own) { srs += rs; srm += rs * mean; }
    }
  }

  // ---- cross-wave combine: haS[mtw], srsP/srmP[mtw]
  haL[0] += __shfl_xor(haL[0], 16); haL[0] += __shfl_xor(haL[0], 32);
  haL[1] += __shfl_xor(haL[1], 16); haL[1] += __shfl_xor(haL[1], 32);
  float sa = srs, sm = srm;
  sa += __shfl_xor(sa, 16); sa += __shfl_xor(sa, 32);
  sm += __shfl_xor(sm, 16); sm += __shfl_xor(sm, 32);
  if (lane == 0 && cg == 0) { srsP[mtw] = sa; srmP[mtw] = sm; }
  if (lane < 16) { haS[mtw][colc0] = haL[0]; haS[mtw][colc0 + 16] = haL[1]; }
  __syncthreads();
  if (t < 128) haS[0][t] += haS[1][t];
  __syncthreads();
  const float srsT = srsP[0] + srsP[1];
  const float srmT = srmP[0] + srmP[1];
  if (t < 256) {
    float dot = 0.f;
    for (int k = 0; k < HID; k += 4) {
      const f32x4 wv4 = *(const f32x4*)&w2[t * HID + k];
      const f32x4 h = *(const f32x4*)&haS[0][k];
      dot += wv4[0] * h[0] + wv4[1] * h[1] + wv4[2] * h[2] + wv4[3] * h[3];
    }
    const float gv = (dot + b2[t] * srsT - srmT) * (1.f / 512.f) * g2[t] + be2[t];
    gS[t] = gv;
    atomicAdd(&mgsum[(b * NSEG + labels[bi]) * DIM + t], gv);
  }
  __syncthreads();
  // ---- K/V split across thread halves; transposed weights = coalesced
  if (t < 256) {
    float kacc = bk[t];
    for (int k = 0; k < DIM; k += 4) {
      const f32x4 g4 = *(const f32x4*)&gS[k];
      kacc += g4[0] * wkT[(k + 0) * DIM + t] + g4[1] * wkT[(k + 1) * DIM + t]
            + g4[2] * wkT[(k + 2) * DIM + t] + g4[3] * wkT[(k + 3) * DIM + t];
    }
    // Kt[b][h=t>>5][d=t&31][k=bi&511] — scattered store, coalesced READ in k5
    Kt[((b * 8 + (t >> 5)) * 32 + (t & 31)) * KTS + (bi & 511)] = kacc;
  } else {
    const int c = t - 256;
    float vacc = bv[c];
    for (int k = 0; k < DIM; k += 4) {
      const f32x4 g4 = *(const f32x4*)&gS[k];
      vacc += g4[0] * wvT[(k + 0) * DIM + c] + g4[1] * wvT[(k + 1) * DIM + c]
            + g4[2] * wvT[(k + 2) * DIM + c] + g4[3] * wvT[(k + 3) * DIM + c];
    }
    Vout[bi * DIM + c] = vacc;
  }
}

// ---------------- K5 v3: 1 row/block, all loads lane-consecutive (unchanged) -------------
__global__ __launch_bounds__(256, 4) void k5_fused(
    fpc features, const int* __restrict__ labels,
    fpc comb, fpc cntf, fpc mgsum,
    fpc Kt, fpc V, fpc wqT, fpc bq, fpc woT, fpc bo,
    float* __restrict__ out)
{
  const int row = blockIdx.x;          // global row 0..1023
  const int b = row >> 9;
  const int t = threadIdx.x;
  const int w = t >> 6;                // wave 0..3 -> heads 2w, 2w+1; cols w*64..w*64+63
  const int l = t & 63;
  __shared__ __align__(16) float E[256];
  __shared__ __align__(16) float Qs[256];
  __shared__ __align__(16) float Px[4][512];
  __shared__ __align__(16) float OcS[256];

  // ---- enh row (all 256 threads, scalar col t)
  {
    const int lab = labels[row];
    const float cn = cntf[b * NSEG + lab];
    const float f = features[row * DIM + t];
    float v = f;
    if (cn >= 2.f) {
      const float ag = comb[(b * NSEG + lab) * DIM + t];
      const float mg = mgsum[(b * NSEG + lab) * DIM + t];
      v = 0.7f * f + 0.3f * (ag + mg / cn);
    }
    E[t] = v;
  }
  __syncthreads();
  // ---- Q proj: lane group (l&15) covers 4 cols, quarter (l>>4) splits k; coalesced wqT
  {
    const int c4 = w * 64 + (l & 15) * 4;
    const int k0 = (l >> 4) * 64;
    f32x4 q4 = {0.f, 0.f, 0.f, 0.f};
    for (int k = k0; k < k0 + 64; ++k) {
      const float e = E[k];
      const f32x4 wv4 = *(const f32x4*)&wqT[k * DIM + c4];
      #pragma unroll
      for (int i = 0; i < 4; ++i) q4[i] += e * wv4[i];
    }
    #pragma unroll
    for (int i = 0; i < 4; ++i) { q4[i] += __shfl_xor(q4[i], 16); q4[i] += __shfl_xor(q4[i], 32); }
    if (l < 16) {
      const f32x4 bq4 = *(const f32x4*)&bq[c4];
      f32x4 o;
      #pragma unroll
      for (int i = 0; i < 4; ++i) o[i] = q4[i] + bq4[i];
      *(f32x4*)&Qs[c4] = o;
    }
  }
  // ---- per-head: scores (Kt, coalesced f32x4 over k) -> wave softmax -> PV -> OcS
  for (int hi = 0; hi < 2; ++hi) {
    const int h = w * 2 + hi;
    f32x4 s4[2] = {{0.f, 0.f, 0.f, 0.f}, {0.f, 0.f, 0.f, 0.f}};
    const long kbase = (long)((b * 8 + h) * 32) * KTS;
    for (int d = 0; d < 32; ++d) {
      const float qd = Qs[h * 32 + d];
      const fpc kr = &Kt[kbase + (long)d * KTS];
      const f32x4 k0v = *(const f32x4*)&kr[l * 4];
      const f32x4 k1v = *(const f32x4*)&kr[256 + l * 4];
      #pragma unroll
      for (int i = 0; i < 4; ++i) { s4[0][i] += qd * k0v[i]; s4[1][i] += qd * k1v[i]; }
    }
    #pragma unroll
    for (int i = 0; i < 4; ++i) {
      s4[0][i] *= 0.1767766952966369f;
      s4[1][i] *= 0.1767766952966369f;
    }
    float mx = s4[0][0];
    #pragma unroll
    for (int i = 1; i < 4; ++i) mx = fmaxf(mx, s4[0][i]);
    #pragma unroll
    for (int i = 0; i < 4; ++i) mx = fmaxf(mx, s4[1][i]);
    #pragma unroll
    for (int off = 1; off < 64; off <<= 1) mx = fmaxf(mx, __shfl_xor(mx, off));
    f32x4 p0, p1;
    float sum = 0.f;
    #pragma unroll
    for (int i = 0; i < 4; ++i) { p0[i] = __expf(s4[0][i] - mx); sum += p0[i]; }
    #pragma unroll
    for (int i = 0; i < 4; ++i) { p1[i] = __expf(s4[1][i] - mx); sum += p1[i]; }
    #pragma unroll
    for (int off = 1; off < 64; off <<= 1) sum += __shfl_xor(sum, off);
    const float ri = 1.f / sum;
    #pragma unroll
    for (int i = 0; i < 4; ++i) { p0[i] *= ri; p1[i] *= ri; }
    *(f32x4*)&Px[w][l * 4] = p0;
    *(f32x4*)&Px[w][256 + l * 4] = p1;
    // PV baseline-style: group (l>>4) = k-quarter, (l&15)*2 = dim pair; V row broadcast
    const int j2 = (l & 15) * 2;
    const int k0 = (l >> 4) * 128;
    float o0 = 0.f, o1 = 0.f;
    for (int k = k0; k < k0 + 128; ++k) {
      const float pv = Px[w][k];
      const float2 vv = *(const float2*)&V[(b * NPTS + k) * DIM + h * 32 + j2];
      o0 += pv * vv.x; o1 += pv * vv.y;
    }
    o0 += __shfl_xor(o0, 16); o1 += __shfl_xor(o1, 16);
    o0 += __shfl_xor(o0, 32); o1 += __shfl_xor(o1, 32);
    if (l < 16) { OcS[h * 32 + j2] = o0; OcS[h * 32 + j2 + 1] = o1; }
  }
  __syncthreads();
  // ---- wo proj + epilogue: same split as Q proj; coalesced woT
  {
    const int c4 = w * 64 + (l & 15) * 4;
    const int j0 = (l >> 4) * 64;
    f32x4 d4 = {0.f, 0.f, 0.f, 0.f};
    for (int j = j0; j < j0 + 64; ++j) {
      const float oc = OcS[j];
      const f32x4 wv4 = *(const f32x4*)&woT[j * DIM + c4];
      #pragma unroll
      for (int i = 0; i < 4; ++i) d4[i] += oc * wv4[i];
    }
    #pragma unroll
    for (int i = 0; i < 4; ++i) { d4[i] += __shfl_xor(d4[i], 16); d4[i] += __shfl_xor(d4[i], 32); }
    if (l < 16) {
      const f32x4 bo4 = *(const f32x4*)&bo[c4];
      const f32x4 e4 = *(const f32x4*)&E[c4];
      f32x4 o;
      #pragma unroll
      for (int i = 0; i < 4; ++i) o[i] = e4[i] + 0.5f * (d4[i] + bo4[i]);
      *(f32x4*)&out[row * DIM + c4] = o;
    }
  }
}

extern "C" void kernel_launch(void* const* d_in, const int* in_sizes, int n_in,
                              void* d_out, int out_size, void* d_ws, size_t ws_size,
                              hipStream_t stream)
{
  fpc coords  = (fpc)d_in[0];
  fpc features= (fpc)d_in[1];
  const int* labels = (const int*)d_in[2];
  fpc ge_w1 = (fpc)d_in[3],  ge_b1 = (fpc)d_in[4],  ge_g1 = (fpc)d_in[5],  ge_be1 = (fpc)d_in[6];
  fpc ge_w2 = (fpc)d_in[7],  ge_b2 = (fpc)d_in[8],  ge_g2 = (fpc)d_in[9],  ge_be2 = (fpc)d_in[10];
  fpc ag_w1 = (fpc)d_in[11], ag_b1 = (fpc)d_in[12], ag_g1 = (fpc)d_in[13], ag_be1 = (fpc)d_in[14];
  fpc ag_w2 = (fpc)d_in[15], ag_b2 = (fpc)d_in[16], ag_g2 = (fpc)d_in[17], ag_be2 = (fpc)d_in[18];
  fpc wq = (fpc)d_in[19], bq = (fpc)d_in[20];
  fpc wk = (fpc)d_in[21], bk = (fpc)d_in[22];
  fpc wv = (fpc)d_in[23], bv = (fpc)d_in[24];
  fpc wo = (fpc)d_in[25], bo = (fpc)d_in[26];

  float* ws = (float*)d_ws;
  float* comb    = ws;                    // 32768
  float* cntf    = comb + 32768;          // 128
  float* Vb      = cntf + 128;            // 262144
  float* Ktb     = Vb + 262144;           // 266240 (2*8*32*520)
  float* mgsum   = Ktb + 266240;          // 32768
  float* gmwF    = mgsum + 32768;         // 8192
  float* uw      = gmwF + 8192;           // 128
  float* tvw     = uw + 128;              // 128
  float* scw     = tvw + 128;             // 8
  float* qfw     = scw + 8;               // 128
  float* wkT     = qfw + 128;             // 65536
  float* wvT     = wkT + 65536;           // 65536
  float* wqT     = wvT + 65536;           // 65536
  float* woT     = wqT + 65536;           // 65536

  k02_prep_agg<<<290, 256, 0, stream>>>(ge_w1, ge_b1, ge_w2, ge_b2,
                                        features, labels, wk, wv, wq, wo,
                                        ag_w1, ag_b1, ag_g1, ag_be1,
                                        ag_w2, ag_b2, ag_g2, ag_be2,
                                        (unsigned short*)gmwF, uw, tvw, scw, qfw,
                                        wkT, wvT, wqT, woT, comb, cntf, mgsum);
  k1_geo<<<1024, 512, 0, stream>>>(coords, labels, ge_g1, ge_be1, ge_w1, ge_b1,
                                   ge_w2, ge_b2, ge_g2, ge_be2,
                                   wkT, bk, wvT, bv,
                                   (const unsigned short*)gmwF, uw, tvw, scw, qfw,
                                   Ktb, Vb, mgsum);
  k5_fused<<<1024, 256, 0, stream>>>(features, labels, comb, cntf, mgsum,
                                     Ktb, Vb, wqT, bq, woT, bo, (float*)d_out);
}